// Round 1
// baseline (844.210 us; speedup 1.0000x reference)
//
#include <hip/hip_runtime.h>
#include <math.h>

// ---------------------------------------------------------------------------
// DQNNet GNN, f16x3 split-precision MFMA GEMMs (error ~2^-22, fp32-equivalent).
//   h = l2norm(relu(x @ W1^T + b1))            [gemm_l1, + fused edge histogram]
//   2x: z = h @ [W2;W3]^T                      [gemm_z, first fused with CSR fill]
//       h = l2norm(relu([z1+b2 | segsum(z2[src])+b3]))   [fin]
//   out = relu(h @ Wd1^T + bd1) @ Wd2^T + bd2  [gemm_head, matvec fused]
//
// v2: barrier-free streaming GEMM.
//   - W pre-packed ONCE into MFMA-fragment-major (hi,lo) f16 buffers (pack_w).
//     Fragment slot = (((hl*8 + t)*2 + ks)*8 + nt)*64 + lane, 16 B each.
//     GEMM waves load W register-direct from L2 (coalesced 16B/lane).
//   - A loaded register-direct from global: lane reads its 8 u32 fragment
//     (32 B); the lh=0/1 halves of a wave tile full 64B lines -> exact traffic.
//   - No LDS in the main loop, no __syncthreads: BM=64, 4 waves/block,
//     3 blocks/CU (__launch_bounds__(256,3)), latency hidden by TLP +
//     1-step register double-buffering.
// h stored as (hi,lo) f16 pairs packed in u32 (same bytes as fp32).
// ---------------------------------------------------------------------------

typedef _Float16 f16x8 __attribute__((ext_vector_type(8)));
typedef float    f32x16 __attribute__((ext_vector_type(16)));

constexpr int DIM = 256;
constexpr int BM  = 64;

__device__ __forceinline__ unsigned pack_pair(float v) {
    _Float16 hi = (_Float16)v;
    _Float16 lo = (_Float16)(v - (float)hi);
    return (unsigned)__builtin_bit_cast(unsigned short, hi)
         | ((unsigned)__builtin_bit_cast(unsigned short, lo) << 16);
}

// ---- one-time W pack: 3 layers, each 256x256 f32 -> fragment-major f16 ----
// dst layout: frag = (((hl*8 + t)*2 + ks)*8 + nt), slot = frag*64 + lane,
// 8 f16 per slot: W[n = nt*32 + (lane&31)][k = t*32 + ks*16 + (lane>>5)*8 + j]
__global__ __launch_bounds__(256)
void pack_w_kernel(const float* __restrict__ WA0, const float* __restrict__ WB0,
                   const float* __restrict__ WA1, const float* __restrict__ WB1,
                   const float* __restrict__ WA2, const float* __restrict__ WB2,
                   _Float16* __restrict__ d0, _Float16* __restrict__ d1,
                   _Float16* __restrict__ d2)
{
    const int layer = (int)blockIdx.x >> 6;
    const int tid   = ((int)blockIdx.x & 63) * 256 + threadIdx.x;  // 0..16383
    const float* WA = layer == 0 ? WA0 : layer == 1 ? WA1 : WA2;
    const float* WB = layer == 0 ? WB0 : layer == 1 ? WB1 : WB2;
    _Float16* dst   = layer == 0 ? d0  : layer == 1 ? d1  : d2;

    const int lane = tid & 63;
    const int frag = tid >> 6;               // 0..255
    const int nt = frag & 7;
    const int ks = (frag >> 3) & 1;
    const int t  = (frag >> 4) & 7;
    const int hl = frag >> 7;
    const int n  = nt * 32 + (lane & 31);
    const int k0 = t * 32 + ks * 16 + (lane >> 5) * 8;
    const float* src = (n < 128) ? &WA[(size_t)n * 256] : &WB[(size_t)(n - 128) * 256];

    f16x8 o;
    #pragma unroll
    for (int j = 0; j < 8; ++j) {
        const float v = src[k0 + j];
        const _Float16 h = (_Float16)v;
        o[j] = hl ? (_Float16)(v - (float)h) : h;
    }
    *(f16x8*)&dst[(size_t)tid * 8] = o;
}

// ---------------------------------------------------------------------------
// Streaming GEMM body. BM=64 rows/block, 4 waves: wr = w>>1 (32-row half),
// wc = w&1 (128-col half). Per wave: acc[4] f32x16 = 32x128 output.
// AMODE: 0 = A is fp32 (split on the fly); 1 = A is (hi,lo)-pair u32.
// EPI:   0 = raw fp32 z; 1 = bias+relu+l2norm -> pair; 2 = bias+relu+matvec.
// ---------------------------------------------------------------------------
template <int AMODE, int EPI>
__device__ __forceinline__
void gemm2_body(const void* __restrict__ Av, const _Float16* __restrict__ Wpk,
                const float* __restrict__ bA, const float* __restrict__ bB,
                void* __restrict__ outv,
                const float* __restrict__ wd2, const float* __restrict__ bd2,
                float* __restrict__ out1, int M)
{
    const int tid  = threadIdx.x;
    const int lane = tid & 63;
    const int w    = tid >> 6;
    const int wr   = w >> 1;
    const int wc   = w & 1;
    const int l31  = lane & 31;
    const int lh   = lane >> 5;
    const int bm0  = (int)blockIdx.x * BM;

    const int arow = bm0 + wr * 32 + l31;
    const int ar   = arow < M ? arow : (M - 1);   // clamp loads, guard stores

    // A: row stride 1024 B (256 x 4B elems either dtype); per step s = t*2+ks
    // the lane's 32B fragment sits at +s*64 (+16 for the second half).
    const char* a_p = (const char*)Av + (size_t)ar * 1024 + lh * 32;

    // W: hi at frag base, lo at +128 frags; step stride = 8 frags = 8192 B;
    // tc stride = 1024 B (immediate-offset friendly).
    const char* wh_p = (const char*)Wpk + (size_t)(wc * 4 * 64 + lane) * 16;
    const char* wl_p = wh_p + 128 * 64 * 16;

    f32x16 acc[4];
    #pragma unroll
    for (int tc = 0; tc < 4; ++tc)
        #pragma unroll
        for (int i = 0; i < 16; ++i) acc[tc][i] = 0.0f;

    uint4 A0[2], A1[2];
    f16x8 W0[4], W1[4], wl[4];

    auto PA = [&](int s, uint4* A) {
        A[0] = *(const uint4*)(a_p + s * 64);
        A[1] = *(const uint4*)(a_p + s * 64 + 16);
    };
    auto PWH = [&](int s, f16x8* W) {
        #pragma unroll
        for (int tc = 0; tc < 4; ++tc)
            W[tc] = *(const f16x8*)(wh_p + s * 8192 + tc * 1024);
    };
    auto WL = [&](int s) {
        #pragma unroll
        for (int tc = 0; tc < 4; ++tc)
            wl[tc] = *(const f16x8*)(wl_p + s * 8192 + tc * 1024);
    };
    auto COMP = [&](const uint4* A, const f16x8* W) {
        f16x8 ah, al;
        if constexpr (AMODE == 1) {
            uint4 uh, ul;
            uh.x = __builtin_amdgcn_perm(A[0].y, A[0].x, 0x05040100u);
            uh.y = __builtin_amdgcn_perm(A[0].w, A[0].z, 0x05040100u);
            uh.z = __builtin_amdgcn_perm(A[1].y, A[1].x, 0x05040100u);
            uh.w = __builtin_amdgcn_perm(A[1].w, A[1].z, 0x05040100u);
            ul.x = __builtin_amdgcn_perm(A[0].y, A[0].x, 0x07060302u);
            ul.y = __builtin_amdgcn_perm(A[0].w, A[0].z, 0x07060302u);
            ul.z = __builtin_amdgcn_perm(A[1].y, A[1].x, 0x07060302u);
            ul.w = __builtin_amdgcn_perm(A[1].w, A[1].z, 0x07060302u);
            ah = __builtin_bit_cast(f16x8, uh);
            al = __builtin_bit_cast(f16x8, ul);
        } else {
            const float fv[8] = {
                __builtin_bit_cast(float, A[0].x), __builtin_bit_cast(float, A[0].y),
                __builtin_bit_cast(float, A[0].z), __builtin_bit_cast(float, A[0].w),
                __builtin_bit_cast(float, A[1].x), __builtin_bit_cast(float, A[1].y),
                __builtin_bit_cast(float, A[1].z), __builtin_bit_cast(float, A[1].w)};
            #pragma unroll
            for (int j = 0; j < 8; ++j) {
                const _Float16 h = (_Float16)fv[j];
                ah[j] = h;
                al[j] = (_Float16)(fv[j] - (float)h);
            }
        }
        // per-acc order matches v1 exactly: ah*wh, ah*wl, al*wh
        #pragma unroll
        for (int tc = 0; tc < 4; ++tc)
            acc[tc] = __builtin_amdgcn_mfma_f32_32x32x16_f16(ah, W[tc], acc[tc], 0, 0, 0);
        #pragma unroll
        for (int tc = 0; tc < 4; ++tc)
            acc[tc] = __builtin_amdgcn_mfma_f32_32x32x16_f16(ah, wl[tc], acc[tc], 0, 0, 0);
        #pragma unroll
        for (int tc = 0; tc < 4; ++tc)
            acc[tc] = __builtin_amdgcn_mfma_f32_32x32x16_f16(al, W[tc], acc[tc], 0, 0, 0);
    };

    PA(0, A0); PWH(0, W0);
    #pragma unroll 1
    for (int s = 0; s < 16; s += 2) {
        WL(s);                                    // lo-frags for step s
        PA(s + 1, A1); PWH(s + 1, W1);            // prefetch step s+1
        COMP(A0, W0);
        WL(s + 1);
        if (s + 2 < 16) { PA(s + 2, A0); PWH(s + 2, W0); }
        COMP(A1, W1);
    }

    // C/D layout (32x32): col = lane&31, row = (reg&3) + 8*(reg>>2) + 4*(lane>>5)

    if constexpr (EPI == 0) {
        float* zz = (float*)outv;
        #pragma unroll
        for (int i = 0; i < 16; ++i) {
            const int rl = wr * 32 + 4 * lh + (i & 3) + 8 * (i >> 2);
            const int gr = bm0 + rl;
            if (gr < M) {
                #pragma unroll
                for (int tc = 0; tc < 4; ++tc)
                    zz[(size_t)gr * 256 + wc * 128 + tc * 32 + l31] = acc[tc][i];
            }
        }
        return;
    }

    {   // bias + relu
        float bias[4];
        #pragma unroll
        for (int tc = 0; tc < 4; ++tc)
            bias[tc] = (wc ? bB : bA)[tc * 32 + l31];
        #pragma unroll
        for (int tc = 0; tc < 4; ++tc)
            #pragma unroll
            for (int i = 0; i < 16; ++i)
                acc[tc][i] = fmaxf(acc[tc][i] + bias[tc], 0.0f);
    }

    if constexpr (EPI == 1) {
        __shared__ float red[128];   // [wc][64 rows] partial sq-sums
        #pragma unroll
        for (int i = 0; i < 16; ++i) {
            float s = 0.f;
            #pragma unroll
            for (int tc = 0; tc < 4; ++tc) s += acc[tc][i] * acc[tc][i];
            #pragma unroll
            for (int m = 1; m < 32; m <<= 1) s += __shfl_xor(s, m);
            if (l31 == i)
                red[wc * 64 + wr * 32 + 4 * lh + (i & 3) + 8 * (i >> 2)] = s;
        }
        __syncthreads();

        unsigned* hpo = (unsigned*)outv;
        #pragma unroll
        for (int i = 0; i < 16; ++i) {
            const int rl  = wr * 32 + 4 * lh + (i & 3) + 8 * (i >> 2);
            const float inv = 1.0f / sqrtf(red[rl] + red[64 + rl]);
            const int gr  = bm0 + rl;
            if (gr < M) {
                #pragma unroll
                for (int tc = 0; tc < 4; ++tc)
                    hpo[(size_t)gr * 256 + wc * 128 + tc * 32 + l31] =
                        pack_pair(acc[tc][i] * inv);
            }
        }
        return;
    }

    if constexpr (EPI == 2) {
        __shared__ float red[128];
        float wv[4];
        #pragma unroll
        for (int tc = 0; tc < 4; ++tc) wv[tc] = wd2[wc * 128 + tc * 32 + l31];
        #pragma unroll
        for (int i = 0; i < 16; ++i) {
            float s = 0.f;
            #pragma unroll
            for (int tc = 0; tc < 4; ++tc) s += acc[tc][i] * wv[tc];
            #pragma unroll
            for (int m = 1; m < 32; m <<= 1) s += __shfl_xor(s, m);
            if (l31 == i)
                red[wc * 64 + wr * 32 + 4 * lh + (i & 3) + 8 * (i >> 2)] = s;
        }
        __syncthreads();
        if (tid < 64) {
            const int gr = bm0 + tid;
            if (gr < M) out1[gr] = red[tid] + red[64 + tid] + bd2[0];
        }
    }
}

// ---- layer-1 GEMM with fused edge histogram (extra blocks past gb) ----
__global__ __launch_bounds__(256, 3)
void gemm_l1(const float* __restrict__ x, const _Float16* __restrict__ wpk,
             const float* __restrict__ bA, const float* __restrict__ bB,
             unsigned* __restrict__ hp, int M, int gb,
             const int* __restrict__ ei, int E, int* __restrict__ cnt)
{
    if ((int)blockIdx.x < gb) {
        gemm2_body<0, 1>(x, wpk, bA, bB, hp, nullptr, nullptr, nullptr, M);
    } else {
        const int base = ((int)blockIdx.x - gb) * 1024 + threadIdx.x;
        #pragma unroll
        for (int k = 0; k < 4; ++k) {
            const int e = base + k * 256;
            if (e < E) atomicAdd(&cnt[ei[E + e]], 1);
        }
    }
}

// ---- z GEMM; first instance fuses the CSR fill (extra blocks past gb) ----
template <int DO_FILL>
__global__ __launch_bounds__(256, 3)
void gemm_z(const void* __restrict__ Av, const _Float16* __restrict__ wpk,
            float* __restrict__ z, int M, int gb,
            const int* __restrict__ ei, int E,
            int* __restrict__ cursor, int* __restrict__ esrc)
{
    if ((int)blockIdx.x < gb) {
        gemm2_body<1, 0>(Av, wpk, nullptr, nullptr, z, nullptr, nullptr, nullptr, M);
    } else if (DO_FILL) {
        const int base = ((int)blockIdx.x - gb) * 1024 + threadIdx.x;
        #pragma unroll
        for (int k = 0; k < 4; ++k) {
            const int e = base + k * 256;
            if (e < E) {
                int d = ei[E + e];
                int p = atomicAdd(&cursor[d], 1);
                esrc[p] = ei[e];
            }
        }
    }
}

__global__ __launch_bounds__(256, 3)
void gemm_head(const void* __restrict__ Av, const _Float16* __restrict__ wpk,
               const float* __restrict__ bA, const float* __restrict__ bB,
               const float* __restrict__ wd2, const float* __restrict__ bd2,
               float* __restrict__ out1, int M)
{
    gemm2_body<1, 2>(Av, wpk, bA, bB, nullptr, wd2, bd2, out1, M);
}

// ------------------------- scans -------------------------

__global__ void scan1_kernel(const int* __restrict__ cnt, int n,
                             int* __restrict__ rp, int* __restrict__ sums)
{
    __shared__ int sm[1024];
    const int tid = threadIdx.x;
    const int i = blockIdx.x * 1024 + tid;
    const int v = (i < n) ? cnt[i] : 0;
    sm[tid] = v;
    __syncthreads();
    for (int off = 1; off < 1024; off <<= 1) {
        int t = (tid >= off) ? sm[tid - off] : 0;
        __syncthreads();
        sm[tid] += t;
        __syncthreads();
    }
    if (i < n) rp[i] = sm[tid] - v;
    if (tid == 1023) sums[blockIdx.x] = sm[tid];
}

__global__ void scan2_kernel(int* __restrict__ sums, int n)
{
    __shared__ int sm[128];
    const int tid = threadIdx.x;
    const int v = (tid < n) ? sums[tid] : 0;
    sm[tid] = v;
    __syncthreads();
    for (int off = 1; off < 128; off <<= 1) {
        int t = (tid >= off) ? sm[tid - off] : 0;
        __syncthreads();
        sm[tid] += t;
        __syncthreads();
    }
    if (tid < n) sums[tid] = sm[tid] - v;
}

__global__ void scan3_kernel(int* __restrict__ rp, const int* __restrict__ sums,
                             int* __restrict__ cursor, int n, int E)
{
    int i = blockIdx.x * blockDim.x + threadIdx.x;
    if (i < n) {
        int v = rp[i] + sums[i >> 10];
        rp[i] = v;
        cursor[i] = v;
    }
    if (i == 0) rp[n] = E;
}

// ---- finalize: h[v] = l2norm(relu([z1[v]+b2 | segsum(z2[src])+b3])) ----
// One wave per node. Edge indices preloaded 64-wide (one coalesced load),
// broadcast via v_readlane -> gather addresses come from the SCALAR unit
// (global_load_dwordx2 v, voff, s[saddr]); 4 independent accumulators keep
// 4 gathers of 512 B in flight per wave.
__global__ __launch_bounds__(256)
void fin_kernel(const float* __restrict__ z, const int* __restrict__ rp,
                const int* __restrict__ esrc,
                const float* __restrict__ b2, const float* __restrict__ b3,
                unsigned* __restrict__ hp, int M)
{
    const int v    = blockIdx.x * 4 + (threadIdx.x >> 6);
    const int lane = threadIdx.x & 63;
    if (v >= M) return;
    const int beg = rp[v], end = rp[v + 1];
    const int deg = end - beg;

    const float2 z1 = *(const float2*)&z[(size_t)v * DIM + lane * 2];
    const float2 c2 = *(const float2*)&b2[lane * 2];
    const float2 c3 = *(const float2*)&b3[lane * 2];

    const float* z2 = z + 128;
    float ax0 = 0.f, ay0 = 0.f, ax1 = 0.f, ay1 = 0.f;
    float ax2 = 0.f, ay2 = 0.f, ax3 = 0.f, ay3 = 0.f;

    for (int base = 0; base < deg; base += 64) {
        const int cnt = min(64, deg - base);
        int myidx = 0;
        if (lane < cnt) myidx = esrc[beg + base + lane];
        int j = 0;
        for (; j + 3 < cnt; j += 4) {
            const int s0 = __builtin_amdgcn_readlane(myidx, j);
            const int s1 = __builtin_amdgcn_readlane(myidx, j + 1);
            const int s2 = __builtin_amdgcn_readlane(myidx, j + 2);
            const int s3 = __builtin_amdgcn_readlane(myidx, j + 3);
            const float2 g0 = *(const float2*)&z2[(size_t)s0 * DIM + lane * 2];
            const float2 g1 = *(const float2*)&z2[(size_t)s1 * DIM + lane * 2];
            const float2 g2 = *(const float2*)&z2[(size_t)s2 * DIM + lane * 2];
            const float2 g3 = *(const float2*)&z2[(size_t)s3 * DIM + lane * 2];
            ax0 += g0.x; ay0 += g0.y;
            ax1 += g1.x; ay1 += g1.y;
            ax2 += g2.x; ay2 += g2.y;
            ax3 += g3.x; ay3 += g3.y;
        }
        for (; j < cnt; ++j) {
            const int s0 = __builtin_amdgcn_readlane(myidx, j);
            const float2 g0 = *(const float2*)&z2[(size_t)s0 * DIM + lane * 2];
            ax0 += g0.x; ay0 += g0.y;
        }
    }
    const float sx = (ax0 + ax1) + (ax2 + ax3);
    const float sy = (ay0 + ay1) + (ay2 + ay3);

    const float u1x = fmaxf(z1.x + c2.x, 0.f), u1y = fmaxf(z1.y + c2.y, 0.f);
    const float u2x = fmaxf(sx + c3.x, 0.f),  u2y = fmaxf(sy + c3.y, 0.f);

    float ss = u1x * u1x + u1y * u1y + u2x * u2x + u2y * u2y;
    #pragma unroll
    for (int off = 32; off > 0; off >>= 1) ss += __shfl_xor(ss, off);
    const float inv = 1.0f / sqrtf(ss);

    uint2 p1; p1.x = pack_pair(u1x * inv); p1.y = pack_pair(u1y * inv);
    uint2 p2; p2.x = pack_pair(u2x * inv); p2.y = pack_pair(u2y * inv);
    *(uint2*)&hp[(size_t)v * DIM + lane * 2]       = p1;
    *(uint2*)&hp[(size_t)v * DIM + 128 + lane * 2] = p2;
}

// ------------------------- launch -------------------------

extern "C" void kernel_launch(void* const* d_in, const int* in_sizes, int n_in,
                              void* d_out, int out_size, void* d_ws, size_t ws_size,
                              hipStream_t stream)
{
    const float* x   = (const float*)d_in[0];
    const int*   ei  = (const int*)d_in[1];
    const float* W1  = (const float*)d_in[2];
    const float* b1  = (const float*)d_in[3];
    const float* W2  = (const float*)d_in[4];
    const float* b2  = (const float*)d_in[5];
    const float* W3  = (const float*)d_in[6];
    const float* b3  = (const float*)d_in[7];
    const float* Wd1 = (const float*)d_in[8];
    const float* bd1 = (const float*)d_in[9];
    const float* Wd2 = (const float*)d_in[10];
    const float* bd2 = (const float*)d_in[11];
    float* out = (float*)d_out;

    const int M = in_sizes[0] / DIM;   // 100000
    const int E = in_sizes[1] / 2;     // 1600000

    unsigned* hp  = (unsigned*)d_ws;                  // M*256 u32 (hi,lo) pairs
    float*    z   = (float*)(hp + (size_t)M * DIM);   // M*256 f32
    int*   rp     = (int*)(z + (size_t)M * DIM);      // M+1
    int*   cursor = rp + (M + 1);                     // M
    int*   esrc   = cursor + M;                       // E
    int*   sums   = esrc + E;                         // <=128

    // packed weights (256 KB each), 256-B aligned
    size_t woff = (size_t)((char*)(sums + 128) - (char*)d_ws);
    woff = (woff + 255) & ~(size_t)255;
    _Float16* wpk1 = (_Float16*)((char*)d_ws + woff);
    _Float16* wpk2 = wpk1 + 131072;
    _Float16* wpkd = wpk2 + 131072;

    hipMemsetAsync(cursor, 0, sizeof(int) * M, stream);

    // one-time fragment-major (hi,lo) pack of W1, [W2;W3], Wd1
    pack_w_kernel<<<192, 256, 0, stream>>>(
        W1, W1 + 128 * DIM, W2, W3, Wd1, Wd1 + 128 * DIM, wpk1, wpk2, wpkd);

    const int gb  = (M + BM - 1) / BM;       // 1563 gemm blocks
    const int hb  = (E + 1023) / 1024;       // 1563 edge blocks (4 edges/thread)
    const int nb1 = (M + 1023) / 1024;
    const int fb  = (M + 3) / 4;             // fin: 4 nodes (waves) per block

    // layer 1 GEMM + edge histogram (overlapped in one grid)
    gemm_l1<<<gb + hb, 256, 0, stream>>>(
        x, wpk1, b1, b1 + 128, hp, M, gb, ei, E, cursor);

    // prefix-sum -> rp, reset cursor to offsets
    scan1_kernel<<<nb1, 1024, 0, stream>>>(cursor, M, rp, sums);
    scan2_kernel<<<1, 128, 0, stream>>>(sums, nb1);
    scan3_kernel<<<(M + 255) / 256, 256, 0, stream>>>(rp, sums, cursor, M, E);

    // z GEMM #1 + CSR fill (overlapped), then finalize
    gemm_z<1><<<gb + hb, 256, 0, stream>>>(hp, wpk2, z, M, gb, ei, E, cursor, esrc);
    fin_kernel<<<fb, 256, 0, stream>>>(z, rp, esrc, b2, b3, hp, M);

    // z GEMM #2, finalize
    gemm_z<0><<<gb, 256, 0, stream>>>(hp, wpk2, z, M, gb, nullptr, 0, nullptr, nullptr);
    fin_kernel<<<fb, 256, 0, stream>>>(z, rp, esrc, b2, b3, hp, M);

    // head: out = relu(h @ Wd1^T + bd1) @ Wd2^T + bd2
    gemm_head<<<gb, 256, 0, stream>>>(
        hp, wpkd, bd1, bd1 + 128, Wd2, bd2, out, M);
}

// Round 2
// 837.128 us; speedup vs baseline: 1.0085x; 1.0085x over previous
//
#include <hip/hip_runtime.h>
#include <math.h>

// ---------------------------------------------------------------------------
// DQNNet GNN, f16x3 split-precision MFMA GEMMs (error ~2^-22, fp32-equivalent).
//   h = l2norm(relu(x @ W1^T + b1))            [gemm_l1, + fused edge histogram]
//   2x: z = h @ [W2;W3]^T                      [gemm_z, first fused with CSR fill]
//       h = l2norm(relu([z1+b2 | segsum(z2[src])+b3]))   [fin]
//   out = relu(h @ Wd1^T + bd1) @ Wd2^T + bd2  [gemm_head, matvec fused]
//
// v3: barrier-free streaming GEMM with DEEP register pipeline.
//   - W pre-packed ONCE into MFMA-fragment-major (hi,lo) f16 buffers (pack_w).
//   - A double-buffered, prefetched 2 K-steps ahead (covers ~900cy HBM lat).
//   - W-hi double-buffered, prefetched 1 K-step ahead (covers ~300cy L2 lat).
//   - W-lo single-buffered, issued 8 MFMAs before first use (MFMA order
//     ah*wh, al*wh, ah*wl puts lo-fragments last).
//   - No LDS, no __syncthreads in the main loop; 3 blocks/CU, latency hidden
//     by prefetch distance x 12 independent waves/CU.
// h stored as (hi,lo) f16 pairs packed in u32 (same bytes as fp32).
// ---------------------------------------------------------------------------

typedef _Float16 f16x8 __attribute__((ext_vector_type(8)));
typedef float    f32x16 __attribute__((ext_vector_type(16)));

constexpr int DIM = 256;
constexpr int BM  = 64;

__device__ __forceinline__ unsigned pack_pair(float v) {
    _Float16 hi = (_Float16)v;
    _Float16 lo = (_Float16)(v - (float)hi);
    return (unsigned)__builtin_bit_cast(unsigned short, hi)
         | ((unsigned)__builtin_bit_cast(unsigned short, lo) << 16);
}

// ---- one-time W pack: 3 layers, each 256x256 f32 -> fragment-major f16 ----
// dst layout: frag = (((hl*8 + t)*2 + ks)*8 + nt), slot = frag*64 + lane,
// 8 f16 per slot: W[n = nt*32 + (lane&31)][k = t*32 + ks*16 + (lane>>5)*8 + j]
__global__ __launch_bounds__(256)
void pack_w_kernel(const float* __restrict__ WA0, const float* __restrict__ WB0,
                   const float* __restrict__ WA1, const float* __restrict__ WB1,
                   const float* __restrict__ WA2, const float* __restrict__ WB2,
                   _Float16* __restrict__ d0, _Float16* __restrict__ d1,
                   _Float16* __restrict__ d2)
{
    const int layer = (int)blockIdx.x >> 6;
    const int tid   = ((int)blockIdx.x & 63) * 256 + threadIdx.x;  // 0..16383
    const float* WA = layer == 0 ? WA0 : layer == 1 ? WA1 : WA2;
    const float* WB = layer == 0 ? WB0 : layer == 1 ? WB1 : WB2;
    _Float16* dst   = layer == 0 ? d0  : layer == 1 ? d1  : d2;

    const int lane = tid & 63;
    const int frag = tid >> 6;               // 0..255
    const int nt = frag & 7;
    const int ks = (frag >> 3) & 1;
    const int t  = (frag >> 4) & 7;
    const int hl = frag >> 7;
    const int n  = nt * 32 + (lane & 31);
    const int k0 = t * 32 + ks * 16 + (lane >> 5) * 8;
    const float* src = (n < 128) ? &WA[(size_t)n * 256] : &WB[(size_t)(n - 128) * 256];

    f16x8 o;
    #pragma unroll
    for (int j = 0; j < 8; ++j) {
        const float v = src[k0 + j];
        const _Float16 h = (_Float16)v;
        o[j] = hl ? (_Float16)(v - (float)h) : h;
    }
    *(f16x8*)&dst[(size_t)tid * 8] = o;
}

// ---------------------------------------------------------------------------
// Streaming GEMM body. BM=64 rows/block, 4 waves: wr = w>>1 (32-row half),
// wc = w&1 (128-col half). Per wave: acc[4] f32x16 = 32x128 output.
// AMODE: 0 = A is fp32 (split on the fly); 1 = A is (hi,lo)-pair u32.
// EPI:   0 = raw fp32 z; 1 = bias+relu+l2norm -> pair; 2 = bias+relu+matvec.
// ---------------------------------------------------------------------------
template <int AMODE, int EPI>
__device__ __forceinline__
void gemm2_body(const void* __restrict__ Av, const _Float16* __restrict__ Wpk,
                const float* __restrict__ bA, const float* __restrict__ bB,
                void* __restrict__ outv,
                const float* __restrict__ wd2, const float* __restrict__ bd2,
                float* __restrict__ out1, int M)
{
    const int tid  = threadIdx.x;
    const int lane = tid & 63;
    const int w    = tid >> 6;
    const int wr   = w >> 1;
    const int wc   = w & 1;
    const int l31  = lane & 31;
    const int lh   = lane >> 5;
    const int bm0  = (int)blockIdx.x * BM;

    const int arow = bm0 + wr * 32 + l31;
    const int ar   = arow < M ? arow : (M - 1);   // clamp loads, guard stores

    // A: row stride 1024 B; per step s the lane's 32B fragment sits at +s*64.
    const char* a_p = (const char*)Av + (size_t)ar * 1024 + lh * 32;

    // W: hi at frag base, lo at +128 frags; step stride = 8 frags = 8192 B;
    // tc stride = 1024 B (immediate-offset friendly).
    const char* wh_p = (const char*)Wpk + (size_t)(wc * 4 * 64 + lane) * 16;
    const char* wl_p = wh_p + 128 * 64 * 16;

    f32x16 acc[4];
    #pragma unroll
    for (int tc = 0; tc < 4; ++tc)
        #pragma unroll
        for (int i = 0; i < 16; ++i) acc[tc][i] = 0.0f;

    uint4 A0[2], A1[2];
    f16x8 WH0[4], WH1[4], WLb[4];

    auto PA = [&](int s, uint4* A) {
        A[0] = *(const uint4*)(a_p + s * 64);
        A[1] = *(const uint4*)(a_p + s * 64 + 16);
    };
    auto PWH = [&](int s, f16x8* W) {
        #pragma unroll
        for (int tc = 0; tc < 4; ++tc)
            W[tc] = *(const f16x8*)(wh_p + s * 8192 + tc * 1024);
    };
    auto PWL = [&](int s) {
        #pragma unroll
        for (int tc = 0; tc < 4; ++tc)
            WLb[tc] = *(const f16x8*)(wl_p + s * 8192 + tc * 1024);
    };
    auto SPLIT = [&](const uint4* A, f16x8& ah, f16x8& al) {
        if constexpr (AMODE == 1) {
            uint4 uh, ul;
            uh.x = __builtin_amdgcn_perm(A[0].y, A[0].x, 0x05040100u);
            uh.y = __builtin_amdgcn_perm(A[0].w, A[0].z, 0x05040100u);
            uh.z = __builtin_amdgcn_perm(A[1].y, A[1].x, 0x05040100u);
            uh.w = __builtin_amdgcn_perm(A[1].w, A[1].z, 0x05040100u);
            ul.x = __builtin_amdgcn_perm(A[0].y, A[0].x, 0x07060302u);
            ul.y = __builtin_amdgcn_perm(A[0].w, A[0].z, 0x07060302u);
            ul.z = __builtin_amdgcn_perm(A[1].y, A[1].x, 0x07060302u);
            ul.w = __builtin_amdgcn_perm(A[1].w, A[1].z, 0x07060302u);
            ah = __builtin_bit_cast(f16x8, uh);
            al = __builtin_bit_cast(f16x8, ul);
        } else {
            const float fv[8] = {
                __builtin_bit_cast(float, A[0].x), __builtin_bit_cast(float, A[0].y),
                __builtin_bit_cast(float, A[0].z), __builtin_bit_cast(float, A[0].w),
                __builtin_bit_cast(float, A[1].x), __builtin_bit_cast(float, A[1].y),
                __builtin_bit_cast(float, A[1].z), __builtin_bit_cast(float, A[1].w)};
            #pragma unroll
            for (int j = 0; j < 8; ++j) {
                const _Float16 h = (_Float16)fv[j];
                ah[j] = h;
                al[j] = (_Float16)(fv[j] - (float)h);
            }
        }
    };
    auto MF4 = [&](f16x8 a, const f16x8* W) {
        #pragma unroll
        for (int tc = 0; tc < 4; ++tc)
            acc[tc] = __builtin_amdgcn_mfma_f32_32x32x16_f16(a, W[tc], acc[tc], 0, 0, 0);
    };

    // prologue: A two steps deep, W-hi two steps deep
    PA(0, A0); PWH(0, WH0);
    PA(1, A1); PWH(1, WH1);

    #pragma unroll 1
    for (int s = 0; s < 16; s += 2) {
        // ---- even sub-step s: uses A0 / WH0 ----
        {
            f16x8 ah, al;
            SPLIT(A0, ah, al);                 // consume A0
            if (s + 2 < 16) PA(s + 2, A0);     // refill: 2-step distance (HBM)
            PWL(s);                            // lo-frags: needed after 8 MFMAs
            MF4(ah, WH0);
            MF4(al, WH0);                      // WH0 now dead
            if (s + 2 < 16) PWH(s + 2, WH0);   // refill: 1.7-step distance (L2)
            MF4(ah, WLb);
        }
        // ---- odd sub-step s+1: uses A1 / WH1 ----
        {
            f16x8 ah, al;
            SPLIT(A1, ah, al);
            if (s + 3 < 16) PA(s + 3, A1);
            PWL(s + 1);
            MF4(ah, WH1);
            MF4(al, WH1);
            if (s + 3 < 16) PWH(s + 3, WH1);
            MF4(ah, WLb);
        }
    }

    // C/D layout (32x32): col = lane&31, row = (reg&3) + 8*(reg>>2) + 4*(lane>>5)

    if constexpr (EPI == 0) {
        float* zz = (float*)outv;
        #pragma unroll
        for (int i = 0; i < 16; ++i) {
            const int rl = wr * 32 + 4 * lh + (i & 3) + 8 * (i >> 2);
            const int gr = bm0 + rl;
            if (gr < M) {
                #pragma unroll
                for (int tc = 0; tc < 4; ++tc)
                    zz[(size_t)gr * 256 + wc * 128 + tc * 32 + l31] = acc[tc][i];
            }
        }
        return;
    }

    {   // bias + relu
        float bias[4];
        #pragma unroll
        for (int tc = 0; tc < 4; ++tc)
            bias[tc] = (wc ? bB : bA)[tc * 32 + l31];
        #pragma unroll
        for (int tc = 0; tc < 4; ++tc)
            #pragma unroll
            for (int i = 0; i < 16; ++i)
                acc[tc][i] = fmaxf(acc[tc][i] + bias[tc], 0.0f);
    }

    if constexpr (EPI == 1) {
        __shared__ float red[128];   // [wc][64 rows] partial sq-sums
        #pragma unroll
        for (int i = 0; i < 16; ++i) {
            float s = 0.f;
            #pragma unroll
            for (int tc = 0; tc < 4; ++tc) s += acc[tc][i] * acc[tc][i];
            #pragma unroll
            for (int m = 1; m < 32; m <<= 1) s += __shfl_xor(s, m);
            if (l31 == i)
                red[wc * 64 + wr * 32 + 4 * lh + (i & 3) + 8 * (i >> 2)] = s;
        }
        __syncthreads();

        unsigned* hpo = (unsigned*)outv;
        #pragma unroll
        for (int i = 0; i < 16; ++i) {
            const int rl  = wr * 32 + 4 * lh + (i & 3) + 8 * (i >> 2);
            const float inv = 1.0f / sqrtf(red[rl] + red[64 + rl]);
            const int gr  = bm0 + rl;
            if (gr < M) {
                #pragma unroll
                for (int tc = 0; tc < 4; ++tc)
                    hpo[(size_t)gr * 256 + wc * 128 + tc * 32 + l31] =
                        pack_pair(acc[tc][i] * inv);
            }
        }
        return;
    }

    if constexpr (EPI == 2) {
        __shared__ float red[128];
        float wv[4];
        #pragma unroll
        for (int tc = 0; tc < 4; ++tc) wv[tc] = wd2[wc * 128 + tc * 32 + l31];
        #pragma unroll
        for (int i = 0; i < 16; ++i) {
            float s = 0.f;
            #pragma unroll
            for (int tc = 0; tc < 4; ++tc) s += acc[tc][i] * wv[tc];
            #pragma unroll
            for (int m = 1; m < 32; m <<= 1) s += __shfl_xor(s, m);
            if (l31 == i)
                red[wc * 64 + wr * 32 + 4 * lh + (i & 3) + 8 * (i >> 2)] = s;
        }
        __syncthreads();
        if (tid < 64) {
            const int gr = bm0 + tid;
            if (gr < M) out1[gr] = red[tid] + red[64 + tid] + bd2[0];
        }
    }
}

// ---- layer-1 GEMM with fused edge histogram (extra blocks past gb) ----
__global__ __launch_bounds__(256, 3)
void gemm_l1(const float* __restrict__ x, const _Float16* __restrict__ wpk,
             const float* __restrict__ bA, const float* __restrict__ bB,
             unsigned* __restrict__ hp, int M, int gb,
             const int* __restrict__ ei, int E, int* __restrict__ cnt)
{
    if ((int)blockIdx.x < gb) {
        gemm2_body<0, 1>(x, wpk, bA, bB, hp, nullptr, nullptr, nullptr, M);
    } else {
        const int base = ((int)blockIdx.x - gb) * 1024 + threadIdx.x;
        #pragma unroll
        for (int k = 0; k < 4; ++k) {
            const int e = base + k * 256;
            if (e < E) atomicAdd(&cnt[ei[E + e]], 1);
        }
    }
}

// ---- z GEMM; first instance fuses the CSR fill (extra blocks past gb) ----
template <int DO_FILL>
__global__ __launch_bounds__(256, 3)
void gemm_z(const void* __restrict__ Av, const _Float16* __restrict__ wpk,
            float* __restrict__ z, int M, int gb,
            const int* __restrict__ ei, int E,
            int* __restrict__ cursor, int* __restrict__ esrc)
{
    if ((int)blockIdx.x < gb) {
        gemm2_body<1, 0>(Av, wpk, nullptr, nullptr, z, nullptr, nullptr, nullptr, M);
    } else if (DO_FILL) {
        const int base = ((int)blockIdx.x - gb) * 1024 + threadIdx.x;
        #pragma unroll
        for (int k = 0; k < 4; ++k) {
            const int e = base + k * 256;
            if (e < E) {
                int d = ei[E + e];
                int p = atomicAdd(&cursor[d], 1);
                esrc[p] = ei[e];
            }
        }
    }
}

__global__ __launch_bounds__(256, 3)
void gemm_head(const void* __restrict__ Av, const _Float16* __restrict__ wpk,
               const float* __restrict__ bA, const float* __restrict__ bB,
               const float* __restrict__ wd2, const float* __restrict__ bd2,
               float* __restrict__ out1, int M)
{
    gemm2_body<1, 2>(Av, wpk, bA, bB, nullptr, wd2, bd2, out1, M);
}

// ------------------------- scans -------------------------

__global__ void scan1_kernel(const int* __restrict__ cnt, int n,
                             int* __restrict__ rp, int* __restrict__ sums)
{
    __shared__ int sm[1024];
    const int tid = threadIdx.x;
    const int i = blockIdx.x * 1024 + tid;
    const int v = (i < n) ? cnt[i] : 0;
    sm[tid] = v;
    __syncthreads();
    for (int off = 1; off < 1024; off <<= 1) {
        int t = (tid >= off) ? sm[tid - off] : 0;
        __syncthreads();
        sm[tid] += t;
        __syncthreads();
    }
    if (i < n) rp[i] = sm[tid] - v;
    if (tid == 1023) sums[blockIdx.x] = sm[tid];
}

__global__ void scan2_kernel(int* __restrict__ sums, int n)
{
    __shared__ int sm[128];
    const int tid = threadIdx.x;
    const int v = (tid < n) ? sums[tid] : 0;
    sm[tid] = v;
    __syncthreads();
    for (int off = 1; off < 128; off <<= 1) {
        int t = (tid >= off) ? sm[tid - off] : 0;
        __syncthreads();
        sm[tid] += t;
        __syncthreads();
    }
    if (tid < n) sums[tid] = sm[tid] - v;
}

__global__ void scan3_kernel(int* __restrict__ rp, const int* __restrict__ sums,
                             int* __restrict__ cursor, int n, int E)
{
    int i = blockIdx.x * blockDim.x + threadIdx.x;
    if (i < n) {
        int v = rp[i] + sums[i >> 10];
        rp[i] = v;
        cursor[i] = v;
    }
    if (i == 0) rp[n] = E;
}

// ---- finalize: h[v] = l2norm(relu([z1[v]+b2 | segsum(z2[src])+b3])) ----
// One wave per node. Edge indices preloaded 64-wide (one coalesced load),
// broadcast via v_readlane -> gather addresses come from the SCALAR unit
// (global_load_dwordx2 v, voff, s[saddr]); 4 independent accumulators keep
// 4 gathers of 512 B in flight per wave.
__global__ __launch_bounds__(256)
void fin_kernel(const float* __restrict__ z, const int* __restrict__ rp,
                const int* __restrict__ esrc,
                const float* __restrict__ b2, const float* __restrict__ b3,
                unsigned* __restrict__ hp, int M)
{
    const int v    = blockIdx.x * 4 + (threadIdx.x >> 6);
    const int lane = threadIdx.x & 63;
    if (v >= M) return;
    const int beg = rp[v], end = rp[v + 1];
    const int deg = end - beg;

    const float2 z1 = *(const float2*)&z[(size_t)v * DIM + lane * 2];
    const float2 c2 = *(const float2*)&b2[lane * 2];
    const float2 c3 = *(const float2*)&b3[lane * 2];

    const float* z2 = z + 128;
    float ax0 = 0.f, ay0 = 0.f, ax1 = 0.f, ay1 = 0.f;
    float ax2 = 0.f, ay2 = 0.f, ax3 = 0.f, ay3 = 0.f;

    for (int base = 0; base < deg; base += 64) {
        const int cnt = min(64, deg - base);
        int myidx = 0;
        if (lane < cnt) myidx = esrc[beg + base + lane];
        int j = 0;
        for (; j + 3 < cnt; j += 4) {
            const int s0 = __builtin_amdgcn_readlane(myidx, j);
            const int s1 = __builtin_amdgcn_readlane(myidx, j + 1);
            const int s2 = __builtin_amdgcn_readlane(myidx, j + 2);
            const int s3 = __builtin_amdgcn_readlane(myidx, j + 3);
            const float2 g0 = *(const float2*)&z2[(size_t)s0 * DIM + lane * 2];
            const float2 g1 = *(const float2*)&z2[(size_t)s1 * DIM + lane * 2];
            const float2 g2 = *(const float2*)&z2[(size_t)s2 * DIM + lane * 2];
            const float2 g3 = *(const float2*)&z2[(size_t)s3 * DIM + lane * 2];
            ax0 += g0.x; ay0 += g0.y;
            ax1 += g1.x; ay1 += g1.y;
            ax2 += g2.x; ay2 += g2.y;
            ax3 += g3.x; ay3 += g3.y;
        }
        for (; j < cnt; ++j) {
            const int s0 = __builtin_amdgcn_readlane(myidx, j);
            const float2 g0 = *(const float2*)&z2[(size_t)s0 * DIM + lane * 2];
            ax0 += g0.x; ay0 += g0.y;
        }
    }
    const float sx = (ax0 + ax1) + (ax2 + ax3);
    const float sy = (ay0 + ay1) + (ay2 + ay3);

    const float u1x = fmaxf(z1.x + c2.x, 0.f), u1y = fmaxf(z1.y + c2.y, 0.f);
    const float u2x = fmaxf(sx + c3.x, 0.f),  u2y = fmaxf(sy + c3.y, 0.f);

    float ss = u1x * u1x + u1y * u1y + u2x * u2x + u2y * u2y;
    #pragma unroll
    for (int off = 32; off > 0; off >>= 1) ss += __shfl_xor(ss, off);
    const float inv = 1.0f / sqrtf(ss);

    uint2 p1; p1.x = pack_pair(u1x * inv); p1.y = pack_pair(u1y * inv);
    uint2 p2; p2.x = pack_pair(u2x * inv); p2.y = pack_pair(u2y * inv);
    *(uint2*)&hp[(size_t)v * DIM + lane * 2]       = p1;
    *(uint2*)&hp[(size_t)v * DIM + 128 + lane * 2] = p2;
}

// ------------------------- launch -------------------------

extern "C" void kernel_launch(void* const* d_in, const int* in_sizes, int n_in,
                              void* d_out, int out_size, void* d_ws, size_t ws_size,
                              hipStream_t stream)
{
    const float* x   = (const float*)d_in[0];
    const int*   ei  = (const int*)d_in[1];
    const float* W1  = (const float*)d_in[2];
    const float* b1  = (const float*)d_in[3];
    const float* W2  = (const float*)d_in[4];
    const float* b2  = (const float*)d_in[5];
    const float* W3  = (const float*)d_in[6];
    const float* b3  = (const float*)d_in[7];
    const float* Wd1 = (const float*)d_in[8];
    const float* bd1 = (const float*)d_in[9];
    const float* Wd2 = (const float*)d_in[10];
    const float* bd2 = (const float*)d_in[11];
    float* out = (float*)d_out;

    const int M = in_sizes[0] / DIM;   // 100000
    const int E = in_sizes[1] / 2;     // 1600000

    unsigned* hp  = (unsigned*)d_ws;                  // M*256 u32 (hi,lo) pairs
    float*    z   = (float*)(hp + (size_t)M * DIM);   // M*256 f32
    int*   rp     = (int*)(z + (size_t)M * DIM);      // M+1
    int*   cursor = rp + (M + 1);                     // M
    int*   esrc   = cursor + M;                       // E
    int*   sums   = esrc + E;                         // <=128

    // packed weights (256 KB each), 256-B aligned
    size_t woff = (size_t)((char*)(sums + 128) - (char*)d_ws);
    woff = (woff + 255) & ~(size_t)255;
    _Float16* wpk1 = (_Float16*)((char*)d_ws + woff);
    _Float16* wpk2 = wpk1 + 131072;
    _Float16* wpkd = wpk2 + 131072;

    hipMemsetAsync(cursor, 0, sizeof(int) * M, stream);

    // one-time fragment-major (hi,lo) pack of W1, [W2;W3], Wd1
    pack_w_kernel<<<192, 256, 0, stream>>>(
        W1, W1 + 128 * DIM, W2, W3, Wd1, Wd1 + 128 * DIM, wpk1, wpk2, wpkd);

    const int gb  = (M + BM - 1) / BM;       // 1563 gemm blocks
    const int hb  = (E + 1023) / 1024;       // 1563 edge blocks (4 edges/thread)
    const int nb1 = (M + 1023) / 1024;
    const int fb  = (M + 3) / 4;             // fin: 4 nodes (waves) per block

    // layer 1 GEMM + edge histogram (overlapped in one grid)
    gemm_l1<<<gb + hb, 256, 0, stream>>>(
        x, wpk1, b1, b1 + 128, hp, M, gb, ei, E, cursor);

    // prefix-sum -> rp, reset cursor to offsets
    scan1_kernel<<<nb1, 1024, 0, stream>>>(cursor, M, rp, sums);
    scan2_kernel<<<1, 128, 0, stream>>>(sums, nb1);
    scan3_kernel<<<(M + 255) / 256, 256, 0, stream>>>(rp, sums, cursor, M, E);

    // z GEMM #1 + CSR fill (overlapped), then finalize
    gemm_z<1><<<gb + hb, 256, 0, stream>>>(hp, wpk2, z, M, gb, ei, E, cursor, esrc);
    fin_kernel<<<fb, 256, 0, stream>>>(z, rp, esrc, b2, b3, hp, M);

    // z GEMM #2, finalize
    gemm_z<0><<<gb, 256, 0, stream>>>(hp, wpk2, z, M, gb, nullptr, 0, nullptr, nullptr);
    fin_kernel<<<fb, 256, 0, stream>>>(z, rp, esrc, b2, b3, hp, M);

    // head: out = relu(h @ Wd1^T + bd1) @ Wd2^T + bd2
    gemm_head<<<gb, 256, 0, stream>>>(
        hp, wpkd, bd1, bd1 + 128, Wd2, bd2, out, M);
}

// Round 3
// 722.283 us; speedup vs baseline: 1.1688x; 1.1590x over previous
//
#include <hip/hip_runtime.h>
#include <math.h>

// ---------------------------------------------------------------------------
// DQNNet GNN, f16x3 split-precision MFMA GEMMs (error ~2^-22, fp32-equivalent).
//   h = l2norm(relu(x @ W1^T + b1))            [gemm_l1, + fused bucket-scatter]
//   2x: z = h @ [W2;W3]^T                      [gemm_z, pure]
//       h = l2norm(relu([z1+b2 | segsum(z2[src])+b3]))   [fin]
//   out = relu(h @ Wd1^T + bd1) @ Wd2^T + bd2  [gemm_head, matvec fused]
//
// v4: GEMM core reverted to the verified v0 LDS structure. The edge-index
// CSR build (histogram + scan + atomic scatter: ~200 MB scattered RMW +
// 3.2M device atomics) is replaced by a two-level bucket sort with
// coalesced traffic and LDS-local atomics:
//   A1 hist(dst>>8) -> ghist ; A2 scan -> gboff/gcur ; A3 (fused in l1 grid)
//   bucketize edges into ebuf as contiguous runs ; B per-bucket count+scan
//   -> rp, esrc (scatter confined to 16KB L2-resident window).
// h stored as (hi,lo) f16 pairs packed in u32 (same bytes as fp32).
// ---------------------------------------------------------------------------

typedef _Float16 f16x8 __attribute__((ext_vector_type(8)));
typedef float    f32x16 __attribute__((ext_vector_type(16)));

constexpr int DIM = 256;
constexpr int BM  = 128;
constexpr int BK  = 32;    // K-slice per staged tile
constexpr int SA  = 40;    // padded LDS row stride (f16)
constexpr int SW  = 40;
constexpr int NBMAX = 392; // max buckets (256 dsts each): M<=100352

__device__ __forceinline__ unsigned pk_hi2(float a, float b) {
    unsigned short ha = __builtin_bit_cast(unsigned short, (_Float16)a);
    unsigned short hb = __builtin_bit_cast(unsigned short, (_Float16)b);
    return (unsigned)ha | ((unsigned)hb << 16);
}
__device__ __forceinline__ unsigned pk_lo2(float a, float b) {
    _Float16 ha = (_Float16)a, hb = (_Float16)b;
    unsigned short la = __builtin_bit_cast(unsigned short, (_Float16)(a - (float)ha));
    unsigned short lb = __builtin_bit_cast(unsigned short, (_Float16)(b - (float)hb));
    return (unsigned)la | ((unsigned)lb << 16);
}
__device__ __forceinline__ unsigned pack_pair(float v) {
    _Float16 hi = (_Float16)v;
    _Float16 lo = (_Float16)(v - (float)hi);
    return (unsigned)__builtin_bit_cast(unsigned short, hi)
         | ((unsigned)__builtin_bit_cast(unsigned short, lo) << 16);
}

// AMODE: 0 = A is fp32 (split during staging); 1 = A is (hi,lo)-pair u32.
// EPI:   0 = raw fp32 z; 1 = bias+relu+l2norm -> pair; 2 = bias+relu+matvec.
template <int AMODE, int EPI>
__device__ __forceinline__
void gemm_body(const void* __restrict__ Av,
               const float* __restrict__ WA, const float* __restrict__ WB,
               const float* __restrict__ bA, const float* __restrict__ bB,
               void* __restrict__ outv,
               const float* __restrict__ wd2, const float* __restrict__ bd2,
               float* __restrict__ out1, int M)
{
    // LDS: As_hi[128][40] As_lo[128][40] Ws_hi[256][40] Ws_lo[256][40] = 60 KB
    __shared__ __align__(16) _Float16 smem[30720];
    _Float16* As_hi = smem;
    _Float16* As_lo = smem + 5120;
    _Float16* Ws_hi = smem + 10240;
    _Float16* Ws_lo = smem + 20480;

    const int tid  = threadIdx.x;
    const int lane = tid & 63;
    const int w    = tid >> 6;
    const int rh   = w >> 1;
    const int ch   = w & 1;
    const int l31  = lane & 31;
    const int lh   = lane >> 5;
    const int bm0  = blockIdx.x * BM;

    const unsigned* Au = (const unsigned*)Av;
    const int srow = tid >> 3;
    const int sch  = (tid & 7) * 4;

    uint4  pa[4];
    float4 pw[8];

    auto fetchA = [&](int t) {
        const int k0 = t * BK;
        #pragma unroll
        for (int i = 0; i < 4; ++i) {
            const int gr = bm0 + srow + 32 * i;
            uint4 v = {0u, 0u, 0u, 0u};
            if (gr < M) v = *(const uint4*)&Au[(size_t)gr * 256 + k0 + sch];
            pa[i] = v;
        }
    };
    auto fetchW = [&](int t) {
        const int k0 = t * BK;
        #pragma unroll
        for (int i = 0; i < 8; ++i) {
            const int r = srow + 32 * i;
            const float* src = (r < 128) ? &WA[(size_t)r * 256]
                                         : &WB[(size_t)(r - 128) * 256];
            pw[i] = *(const float4*)&src[k0 + sch];
        }
    };
    auto stageA = [&]() {
        #pragma unroll
        for (int i = 0; i < 4; ++i) {
            const int r = srow + 32 * i;
            unsigned h0, h1, l0, l1;
            if (AMODE == 0) {
                const float x0 = __builtin_bit_cast(float, pa[i].x);
                const float x1 = __builtin_bit_cast(float, pa[i].y);
                const float x2 = __builtin_bit_cast(float, pa[i].z);
                const float x3 = __builtin_bit_cast(float, pa[i].w);
                h0 = pk_hi2(x0, x1); h1 = pk_hi2(x2, x3);
                l0 = pk_lo2(x0, x1); l1 = pk_lo2(x2, x3);
            } else {
                h0 = __builtin_amdgcn_perm(pa[i].y, pa[i].x, 0x05040100u);
                l0 = __builtin_amdgcn_perm(pa[i].y, pa[i].x, 0x07060302u);
                h1 = __builtin_amdgcn_perm(pa[i].w, pa[i].z, 0x05040100u);
                l1 = __builtin_amdgcn_perm(pa[i].w, pa[i].z, 0x07060302u);
            }
            uint2 th; th.x = h0; th.y = h1;
            uint2 tl; tl.x = l0; tl.y = l1;
            *(uint2*)&As_hi[r * SA + sch] = th;
            *(uint2*)&As_lo[r * SA + sch] = tl;
        }
    };
    auto stageW = [&]() {
        #pragma unroll
        for (int i = 0; i < 8; ++i) {
            const int r = srow + 32 * i;
            uint2 th; th.x = pk_hi2(pw[i].x, pw[i].y); th.y = pk_hi2(pw[i].z, pw[i].w);
            uint2 tl; tl.x = pk_lo2(pw[i].x, pw[i].y); tl.y = pk_lo2(pw[i].z, pw[i].w);
            *(uint2*)&Ws_hi[r * SW + sch] = th;
            *(uint2*)&Ws_lo[r * SW + sch] = tl;
        }
    };

    f32x16 acc[2][4];
    #pragma unroll
    for (int tr = 0; tr < 2; ++tr)
        #pragma unroll
        for (int tc = 0; tc < 4; ++tc)
            #pragma unroll
            for (int i = 0; i < 16; ++i) acc[tr][tc][i] = 0.0f;

    fetchA(0); fetchW(0);

    #pragma unroll 1
    for (int t = 0; t < DIM / BK; ++t) {
        stageA(); stageW();
        __syncthreads();
        if (t < DIM / BK - 1) { fetchA(t + 1); fetchW(t + 1); }

        #pragma unroll
        for (int ks = 0; ks < 2; ++ks) {
            f16x8 ah[2], al[2], wh[4], wl[4];
            #pragma unroll
            for (int tr = 0; tr < 2; ++tr) {
                const int off = (rh * 64 + tr * 32 + l31) * SA + ks * 16 + lh * 8;
                ah[tr] = *(const f16x8*)&As_hi[off];
                al[tr] = *(const f16x8*)&As_lo[off];
            }
            #pragma unroll
            for (int tc = 0; tc < 4; ++tc) {
                const int off = (ch * 128 + tc * 32 + l31) * SW + ks * 16 + lh * 8;
                wh[tc] = *(const f16x8*)&Ws_hi[off];
                wl[tc] = *(const f16x8*)&Ws_lo[off];
            }
            #pragma unroll
            for (int tr = 0; tr < 2; ++tr)
                #pragma unroll
                for (int tc = 0; tc < 4; ++tc) {
                    acc[tr][tc] = __builtin_amdgcn_mfma_f32_32x32x16_f16(ah[tr], wh[tc], acc[tr][tc], 0, 0, 0);
                    acc[tr][tc] = __builtin_amdgcn_mfma_f32_32x32x16_f16(ah[tr], wl[tc], acc[tr][tc], 0, 0, 0);
                    acc[tr][tc] = __builtin_amdgcn_mfma_f32_32x32x16_f16(al[tr], wh[tc], acc[tr][tc], 0, 0, 0);
                }
        }
        __syncthreads();
    }

    // C/D layout (32x32): col = lane&31, row = (reg&3) + 8*(reg>>2) + 4*(lane>>5)

    if (EPI == 0) {
        float* z = (float*)outv;
        #pragma unroll
        for (int tr = 0; tr < 2; ++tr)
            #pragma unroll
            for (int i = 0; i < 16; ++i) {
                const int r  = rh * 64 + tr * 32 + 4 * lh + (i & 3) + 8 * (i >> 2);
                const int gr = bm0 + r;
                if (gr < M) {
                    #pragma unroll
                    for (int tc = 0; tc < 4; ++tc)
                        z[(size_t)gr * 256 + ch * 128 + tc * 32 + l31] = acc[tr][tc][i];
                }
            }
        return;
    }

    {
        float bias[4];
        #pragma unroll
        for (int tc = 0; tc < 4; ++tc)
            bias[tc] = (ch ? bB : bA)[tc * 32 + l31];
        #pragma unroll
        for (int tr = 0; tr < 2; ++tr)
            #pragma unroll
            for (int tc = 0; tc < 4; ++tc)
                #pragma unroll
                for (int i = 0; i < 16; ++i)
                    acc[tr][tc][i] = fmaxf(acc[tr][tc][i] + bias[tc], 0.0f);
    }

    float* red = (float*)smem;

    if (EPI == 1) {
        float ss[2][16];
        #pragma unroll
        for (int tr = 0; tr < 2; ++tr)
            #pragma unroll
            for (int i = 0; i < 16; ++i) {
                float s = 0.f;
                #pragma unroll
                for (int tc = 0; tc < 4; ++tc) s += acc[tr][tc][i] * acc[tr][tc][i];
                #pragma unroll
                for (int m = 1; m < 32; m <<= 1) s += __shfl_xor(s, m);
                ss[tr][i] = s;
            }
        const int j  = l31;
        const int ji = j & 15, jt = j >> 4;
        red[ch * 128 + rh * 64 + jt * 32 + 4 * lh + (ji & 3) + 8 * (ji >> 2)] = ss[jt][ji];
        __syncthreads();

        unsigned* hp = (unsigned*)outv;
        #pragma unroll
        for (int tr = 0; tr < 2; ++tr)
            #pragma unroll
            for (int i = 0; i < 16; ++i) {
                const int rl = rh * 64 + tr * 32 + 4 * lh + (i & 3) + 8 * (i >> 2);
                const float inv = 1.0f / sqrtf(red[rl] + red[128 + rl]);
                const int gr = bm0 + rl;
                if (gr < M) {
                    #pragma unroll
                    for (int tc = 0; tc < 4; ++tc)
                        hp[(size_t)gr * 256 + ch * 128 + tc * 32 + l31] =
                            pack_pair(acc[tr][tc][i] * inv);
                }
            }
        return;
    }

    // EPI == 2: fused head matvec
    {
        float wv[4];
        #pragma unroll
        for (int tc = 0; tc < 4; ++tc) wv[tc] = wd2[ch * 128 + tc * 32 + l31];
        float dd[2][16];
        #pragma unroll
        for (int tr = 0; tr < 2; ++tr)
            #pragma unroll
            for (int i = 0; i < 16; ++i) {
                float s = 0.f;
                #pragma unroll
                for (int tc = 0; tc < 4; ++tc) s += acc[tr][tc][i] * wv[tc];
                #pragma unroll
                for (int m = 1; m < 32; m <<= 1) s += __shfl_xor(s, m);
                dd[tr][i] = s;
            }
        const int j  = l31;
        const int ji = j & 15, jt = j >> 4;
        red[ch * 128 + rh * 64 + jt * 32 + 4 * lh + (ji & 3) + 8 * (ji >> 2)] = dd[jt][ji];
        __syncthreads();
        if (tid < 128) {
            const int gr = bm0 + tid;
            if (gr < M) out1[gr] = red[tid] + red[128 + tid] + bd2[0];
        }
    }
}

// ---- layer-1 GEMM with fused bucket-scatter A3 (extra blocks past gb) ----
// A3: 128 tail blocks bucketize edges into ebuf as per-(block,bucket)
// contiguous runs. Reads coalesced; 391 global atomics per block.
__global__ __launch_bounds__(256, 2)
void gemm_l1(const void* __restrict__ Av,
             const float* __restrict__ WA, const float* __restrict__ WB,
             const float* __restrict__ bA, const float* __restrict__ bB,
             void* __restrict__ outv, int M, int gb,
             const int* __restrict__ ei, int E, int nb,
             int* __restrict__ gcur, int2* __restrict__ ebuf)
{
    if ((int)blockIdx.x < gb) {
        gemm_body<0, 1>(Av, WA, WB, bA, bB, outv, nullptr, nullptr, nullptr, M);
    } else {
        __shared__ int h[NBMAX], cur[NBMAX];
        const int tid = threadIdx.x;
        const int b   = (int)blockIdx.x - gb;       // 0..127
        for (int t = tid; t < nb; t += 256) h[t] = 0;
        __syncthreads();
        const int EB = (E + 127) >> 7;
        const int e0 = b * EB, e1 = min(E, e0 + EB);
        for (int e = e0 + tid; e < e1; e += 256)
            atomicAdd(&h[ei[E + e] >> 8], 1);
        __syncthreads();
        for (int t = tid; t < nb; t += 256)
            cur[t] = atomicAdd(&gcur[t], h[t]);
        __syncthreads();
        for (int e = e0 + tid; e < e1; e += 256) {
            const int d = ei[E + e];
            const int p = atomicAdd(&cur[d >> 8], 1);
            ebuf[p] = make_int2(d, ei[e]);
        }
    }
}

// ---- z GEMM (pure) ----
__global__ __launch_bounds__(256, 2)
void gemm_z(const void* __restrict__ Av,
            const float* __restrict__ WA, const float* __restrict__ WB,
            void* __restrict__ outv, int M)
{
    gemm_body<1, 0>(Av, WA, WB, nullptr, nullptr, outv, nullptr, nullptr, nullptr, M);
}

__global__ __launch_bounds__(256, 2)
void gemm_head(const void* __restrict__ Av,
               const float* __restrict__ WA, const float* __restrict__ WB,
               const float* __restrict__ bA, const float* __restrict__ bB,
               const float* __restrict__ wd2, const float* __restrict__ bd2,
               float* __restrict__ out1, int M)
{
    gemm_body<1, 2>(Av, WA, WB, bA, bB, nullptr, wd2, bd2, out1, M);
}

// ------------------------- bucket CSR build -------------------------

// A1: global bucket histogram (dst>>8), LDS-aggregated.
__global__ __launch_bounds__(256)
void hist_kernel(const int* __restrict__ ei, int E, int nb,
                 int* __restrict__ ghist)
{
    __shared__ int h[NBMAX];
    const int tid = threadIdx.x;
    for (int t = tid; t < nb; t += 256) h[t] = 0;
    __syncthreads();
    const int EB = (E + 127) >> 7;
    const int e0 = (int)blockIdx.x * EB, e1 = min(E, e0 + EB);
    for (int e = e0 + tid; e < e1; e += 256)
        atomicAdd(&h[ei[E + e] >> 8], 1);
    __syncthreads();
    for (int t = tid; t < nb; t += 256)
        if (h[t]) atomicAdd(&ghist[t], h[t]);
}

// A2: exclusive scan of nb (<512) bucket counts -> gboff, gcur; rp[M]=E.
__global__ __launch_bounds__(512)
void scanb_kernel(const int* __restrict__ ghist, int* __restrict__ gboff,
                  int* __restrict__ gcur, int* __restrict__ rp, int M, int E,
                  int nb)
{
    __shared__ int sm[512];
    const int tid = threadIdx.x;
    const int v = (tid < nb) ? ghist[tid] : 0;
    sm[tid] = v;
    __syncthreads();
    for (int off = 1; off < 512; off <<= 1) {
        int t = (tid >= off) ? sm[tid - off] : 0;
        __syncthreads();
        sm[tid] += t;
        __syncthreads();
    }
    if (tid < nb) {
        const int ex = sm[tid] - v;
        gboff[tid] = ex;
        gcur[tid]  = ex;
    }
    if (tid == 0) { gboff[nb] = E; rp[M] = E; }
}

// B: per 256-dst bucket: exact count + scan -> rp; scatter src -> esrc
// (scatter window = one bucket's contiguous esrc range, L2-resident).
__global__ __launch_bounds__(256)
void bucket_kernel(const int2* __restrict__ ebuf, const int* __restrict__ gboff,
                   int* __restrict__ rp, int* __restrict__ esrc, int M)
{
    const int b   = (int)blockIdx.x;
    const int tid = threadIdx.x;
    const int base = gboff[b], top = gboff[b + 1];
    const int d0 = b << 8;
    __shared__ int c[256], sm[256], cur[256];
    c[tid] = 0;
    __syncthreads();
    for (int j = base + tid; j < top; j += 256)
        atomicAdd(&c[ebuf[j].x - d0], 1);
    __syncthreads();
    sm[tid] = c[tid];
    __syncthreads();
    for (int off = 1; off < 256; off <<= 1) {
        int t = (tid >= off) ? sm[tid - off] : 0;
        __syncthreads();
        sm[tid] += t;
        __syncthreads();
    }
    const int excl = sm[tid] - c[tid];
    const int d = d0 + tid;
    if (d < M) rp[d] = base + excl;
    cur[tid] = base + excl;
    __syncthreads();
    for (int j = base + tid; j < top; j += 256) {
        const int2 e = ebuf[j];
        const int p = atomicAdd(&cur[e.x - d0], 1);
        esrc[p] = e.y;
    }
}

// ---- finalize: h[v] = l2norm(relu([z1[v]+b2 | segsum(z2[src])+b3])) ----
// One wave per node. Edge indices preloaded 64-wide (one coalesced load),
// broadcast via v_readlane; 4 independent accumulators keep 4 gathers of
// 512 B in flight per wave.
__global__ __launch_bounds__(256)
void fin_kernel(const float* __restrict__ z, const int* __restrict__ rp,
                const int* __restrict__ esrc,
                const float* __restrict__ b2, const float* __restrict__ b3,
                unsigned* __restrict__ hp, int M)
{
    const int v    = blockIdx.x * 4 + (threadIdx.x >> 6);
    const int lane = threadIdx.x & 63;
    if (v >= M) return;
    const int beg = rp[v], end = rp[v + 1];
    const int deg = end - beg;

    const float2 z1 = *(const float2*)&z[(size_t)v * DIM + lane * 2];
    const float2 c2 = *(const float2*)&b2[lane * 2];
    const float2 c3 = *(const float2*)&b3[lane * 2];

    const float* z2 = z + 128;
    float ax0 = 0.f, ay0 = 0.f, ax1 = 0.f, ay1 = 0.f;
    float ax2 = 0.f, ay2 = 0.f, ax3 = 0.f, ay3 = 0.f;

    for (int base = 0; base < deg; base += 64) {
        const int cnt = min(64, deg - base);
        int myidx = 0;
        if (lane < cnt) myidx = esrc[beg + base + lane];
        int j = 0;
        for (; j + 3 < cnt; j += 4) {
            const int s0 = __builtin_amdgcn_readlane(myidx, j);
            const int s1 = __builtin_amdgcn_readlane(myidx, j + 1);
            const int s2 = __builtin_amdgcn_readlane(myidx, j + 2);
            const int s3 = __builtin_amdgcn_readlane(myidx, j + 3);
            const float2 g0 = *(const float2*)&z2[(size_t)s0 * DIM + lane * 2];
            const float2 g1 = *(const float2*)&z2[(size_t)s1 * DIM + lane * 2];
            const float2 g2 = *(const float2*)&z2[(size_t)s2 * DIM + lane * 2];
            const float2 g3 = *(const float2*)&z2[(size_t)s3 * DIM + lane * 2];
            ax0 += g0.x; ay0 += g0.y;
            ax1 += g1.x; ay1 += g1.y;
            ax2 += g2.x; ay2 += g2.y;
            ax3 += g3.x; ay3 += g3.y;
        }
        for (; j < cnt; ++j) {
            const int s0 = __builtin_amdgcn_readlane(myidx, j);
            const float2 g0 = *(const float2*)&z2[(size_t)s0 * DIM + lane * 2];
            ax0 += g0.x; ay0 += g0.y;
        }
    }
    const float sx = (ax0 + ax1) + (ax2 + ax3);
    const float sy = (ay0 + ay1) + (ay2 + ay3);

    const float u1x = fmaxf(z1.x + c2.x, 0.f), u1y = fmaxf(z1.y + c2.y, 0.f);
    const float u2x = fmaxf(sx + c3.x, 0.f),  u2y = fmaxf(sy + c3.y, 0.f);

    float ss = u1x * u1x + u1y * u1y + u2x * u2x + u2y * u2y;
    #pragma unroll
    for (int off = 32; off > 0; off >>= 1) ss += __shfl_xor(ss, off);
    const float inv = 1.0f / sqrtf(ss);

    uint2 p1; p1.x = pack_pair(u1x * inv); p1.y = pack_pair(u1y * inv);
    uint2 p2; p2.x = pack_pair(u2x * inv); p2.y = pack_pair(u2y * inv);
    *(uint2*)&hp[(size_t)v * DIM + lane * 2]       = p1;
    *(uint2*)&hp[(size_t)v * DIM + 128 + lane * 2] = p2;
}

// ------------------------- launch -------------------------

extern "C" void kernel_launch(void* const* d_in, const int* in_sizes, int n_in,
                              void* d_out, int out_size, void* d_ws, size_t ws_size,
                              hipStream_t stream)
{
    const float* x   = (const float*)d_in[0];
    const int*   ei  = (const int*)d_in[1];
    const float* W1  = (const float*)d_in[2];
    const float* b1  = (const float*)d_in[3];
    const float* W2  = (const float*)d_in[4];
    const float* b2  = (const float*)d_in[5];
    const float* W3  = (const float*)d_in[6];
    const float* b3  = (const float*)d_in[7];
    const float* Wd1 = (const float*)d_in[8];
    const float* bd1 = (const float*)d_in[9];
    const float* Wd2 = (const float*)d_in[10];
    const float* bd2 = (const float*)d_in[11];
    float* out = (float*)d_out;

    const int M = in_sizes[0] / DIM;   // 100000
    const int E = in_sizes[1] / 2;     // 1600000
    const int nb = (M + 255) >> 8;     // 391 buckets of 256 dsts

    unsigned* hp  = (unsigned*)d_ws;                  // M*256 u32 (hi,lo) pairs
    float*    z   = (float*)(hp + (size_t)M * DIM);   // M*256 f32
    int*   rp     = (int*)(z + (size_t)M * DIM);      // M+1
    int*   esrc   = rp + (M + 1);                     // E
    int*   ghist  = esrc + E;                         // nb
    int*   gboff  = ghist + nb;                       // nb+1
    int*   gcur   = gboff + nb + 1;                   // nb
    // ebuf aliases the z region (z is written only after bucket_kernel ends)
    int2*  ebuf   = (int2*)z;

    hipMemsetAsync(ghist, 0, sizeof(int) * nb, stream);

    const int gb  = (M + BM - 1) / BM;       // 782 gemm blocks
    const int fb  = (M + 3) / 4;             // fin: 4 nodes (waves) per block

    // bucket histogram + scan (cheap, coalesced)
    hist_kernel<<<128, 256, 0, stream>>>(ei, E, nb, ghist);
    scanb_kernel<<<1, 512, 0, stream>>>(ghist, gboff, gcur, rp, M, E, nb);

    // layer-1 GEMM + bucket-scatter A3 (overlapped in one grid)
    gemm_l1<<<gb + 128, 256, 0, stream>>>(
        x, W1, W1 + 128 * DIM, b1, b1 + 128, hp, M, gb, ei, E, nb, gcur, ebuf);

    // per-bucket CSR finalize: rp + esrc
    bucket_kernel<<<nb, 256, 0, stream>>>(ebuf, gboff, rp, esrc, M);

    // z GEMM #1, finalize
    gemm_z<<<gb, 256, 0, stream>>>(hp, W2, W3, z, M);
    fin_kernel<<<fb, 256, 0, stream>>>(z, rp, esrc, b2, b3, hp, M);

    // z GEMM #2, finalize
    gemm_z<<<gb, 256, 0, stream>>>(hp, W2, W3, z, M);
    fin_kernel<<<fb, 256, 0, stream>>>(z, rp, esrc, b2, b3, hp, M);

    // head: out = relu(h @ Wd1^T + bd1) @ Wd2^T + bd2
    gemm_head<<<gb, 256, 0, stream>>>(
        hp, Wd1, Wd1 + 128 * DIM, bd1, bd1 + 128, Wd2, bd2, out, M);
}

// Round 4
// 716.636 us; speedup vs baseline: 1.1780x; 1.0079x over previous
//
#include <hip/hip_runtime.h>
#include <math.h>

// ---------------------------------------------------------------------------
// DQNNet GNN, f16x3 split-precision MFMA GEMMs (error ~2^-22, fp32-equivalent).
//   h = l2norm(relu(x @ W1^T + b1))            [gemm_l1, + fused bucket-scatter]
//   2x: z = h @ [W2;W3]^T                      [gemm_z]
//       h = l2norm(relu([z1+b2 | segsum(z2[src])+b3]))   [fin]
//   out = relu(h @ Wd1^T + bd1) @ Wd2^T + bd2  [gemm_head, matvec fused]
//
// v5: m97-style GEMM core.
//   - A staged via global_load_lds width=16 (no VGPR roundtrip, no staging
//     VALU), double-buffered 16KB tiles, ONE barrier per K-iter; A(t+1)
//     issued right after the barrier -> drained at the NEXT barrier (full
//     iter of latency cover).
//   - Source-address swizzle (chunk ^= row&7 per 128B row-slice) + same XOR
//     on ds_read: bank conflicts at the 4-way floor (rule: swizzle both
//     sides via pre-swizzled per-lane GLOBAL addr, LDS stays linear).
//   - W packed once (fragment-major hi/lo, pack_w) and register-prefetched
//     from L2 one k-step ahead (2 static reg sets, ks-parity indexed).
//   - hi/lo split done at fragment read: 8 perms (packed-u32 A) or cvts
//     (fp32 x) per ks.
// CSR build: v4's two-level bucket sort (unchanged).
// h stored as (hi,lo) f16 pairs packed in u32 (same bytes as fp32).
// ---------------------------------------------------------------------------

typedef _Float16 f16x8 __attribute__((ext_vector_type(8)));
typedef float    f32x16 __attribute__((ext_vector_type(16)));

constexpr int DIM = 256;
constexpr int BM  = 128;
constexpr int NBMAX = 392; // max buckets (256 dsts each): M<=100352

__device__ __forceinline__ unsigned pack_pair(float v) {
    _Float16 hi = (_Float16)v;
    _Float16 lo = (_Float16)(v - (float)hi);
    return (unsigned)__builtin_bit_cast(unsigned short, hi)
         | ((unsigned)__builtin_bit_cast(unsigned short, lo) << 16);
}

__device__ __forceinline__ void glds16(const void* g, void* l) {
    __builtin_amdgcn_global_load_lds(
        (const __attribute__((address_space(1))) unsigned*)g,
        (__attribute__((address_space(3))) unsigned*)l, 16, 0, 0);
}

// ---- one-time W pack: 3 layers, each 256x256 f32 -> fragment-major f16 ----
// dst layout: frag = (((hl*8 + t)*2 + ks)*8 + nt), slot = frag*64 + lane,
// 8 f16 per slot: W[n = nt*32 + (lane&31)][k = t*32 + ks*16 + (lane>>5)*8 + j]
__global__ __launch_bounds__(256)
void pack_w_kernel(const float* __restrict__ WA0, const float* __restrict__ WB0,
                   const float* __restrict__ WA1, const float* __restrict__ WB1,
                   const float* __restrict__ WA2, const float* __restrict__ WB2,
                   _Float16* __restrict__ d0, _Float16* __restrict__ d1,
                   _Float16* __restrict__ d2)
{
    const int layer = (int)blockIdx.x >> 6;
    const int tid   = ((int)blockIdx.x & 63) * 256 + threadIdx.x;  // 0..16383
    const float* WA = layer == 0 ? WA0 : layer == 1 ? WA1 : WA2;
    const float* WB = layer == 0 ? WB0 : layer == 1 ? WB1 : WB2;
    _Float16* dst   = layer == 0 ? d0  : layer == 1 ? d1  : d2;

    const int lane = tid & 63;
    const int frag = tid >> 6;               // 0..255
    const int nt = frag & 7;
    const int ks = (frag >> 3) & 1;
    const int t  = (frag >> 4) & 7;
    const int hl = frag >> 7;
    const int n  = nt * 32 + (lane & 31);
    const int k0 = t * 32 + ks * 16 + (lane >> 5) * 8;
    const float* src = (n < 128) ? &WA[(size_t)n * 256] : &WB[(size_t)(n - 128) * 256];

    f16x8 o;
    #pragma unroll
    for (int j = 0; j < 8; ++j) {
        const float v = src[k0 + j];
        const _Float16 h = (_Float16)v;
        o[j] = hl ? (_Float16)(v - (float)h) : h;
    }
    *(f16x8*)&dst[(size_t)tid * 8] = o;
}

// ---------------------------------------------------------------------------
// GEMM body. BM=128 rows/block, 4 waves: rh = w>>1 (64-row half),
// ch = w&1 (128-col half). Per wave: acc[2][4] f32x16 = 64x128 output.
// AMODE: 0 = A is fp32 (cvt-split at read); 1 = A is (hi,lo)-pair u32 (perm).
// EPI:   0 = raw fp32 z; 1 = bias+relu+l2norm -> pair; 2 = bias+relu+matvec.
// ---------------------------------------------------------------------------
template <int AMODE, int EPI>
__device__ __forceinline__
void gemm2_body(const void* __restrict__ Av, const _Float16* __restrict__ Wpk,
                const float* __restrict__ bA, const float* __restrict__ bB,
                void* __restrict__ outv,
                const float* __restrict__ wd2, const float* __restrict__ bd2,
                float* __restrict__ out1, int M)
{
    // A tile double buffer: [buf][row 0..127][32 u32 = 8 chunks of 16B]
    __shared__ __align__(16) unsigned smem[2][128][32];   // 32 KB

    const int tid  = threadIdx.x;
    const int lane = tid & 63;
    const int w    = tid >> 6;
    const int rh   = w >> 1;
    const int ch   = w & 1;
    const int l31  = lane & 31;
    const int lh   = lane >> 5;
    const int bm0  = (int)blockIdx.x * BM;

    // W: fragment-major; hi at base, lo at +128 frags (131072 B);
    // frag byte = s*8192 + tc*1024 + (ch*4*64 + lane)*16.
    const char* wh_p = (const char*)Wpk + (size_t)(ch * 4 * 64 + lane) * 16;
    const char* wl_p = wh_p + 131072;

    // staging geometry: wave w stages rows [w*32, w*32+32), 4 instrs of
    // 1KB (8 rows x 8 chunks); lane -> (row = +lane>>3, chunk = lane&7).
    const int srb  = w * 32;
    const int srow = lane >> 3;
    const int scp  = lane & 7;

    f32x16 acc[2][4];
    #pragma unroll
    for (int tr = 0; tr < 2; ++tr)
        #pragma unroll
        for (int tc = 0; tc < 4; ++tc)
            #pragma unroll
            for (int i = 0; i < 16; ++i) acc[tr][tc][i] = 0.0f;

    f16x8 WH0[4], WL0[4], WH1[4], WL1[4];

    auto STAGE = [&](int t, int b) {
        #pragma unroll
        for (int i = 0; i < 4; ++i) {
            const int r  = srb + i * 8 + srow;
            const int rg = min(bm0 + r, M - 1);          // clamp; stores guarded
            const int cl = scp ^ (r & 7);                // source pre-swizzle
            glds16((const char*)Av + (size_t)rg * 1024 + t * 128 + cl * 16,
                   (void*)&smem[b][srb + i * 8][0]);     // uniform base +lane*16
        }
    };
    auto PW = [&](int s, f16x8* WH, f16x8* WL) {
        #pragma unroll
        for (int tc = 0; tc < 4; ++tc) {
            WH[tc] = *(const f16x8*)(wh_p + (size_t)s * 8192 + tc * 1024);
            WL[tc] = *(const f16x8*)(wl_p + (size_t)s * 8192 + tc * 1024);
        }
    };
    auto LOADA = [&](int b, int ks, f16x8* ah, f16x8* al) {
        #pragma unroll
        for (int tr = 0; tr < 2; ++tr) {
            const int r  = rh * 64 + tr * 32 + l31;
            const int sw = r & 7;
            const int c0 = ks * 4 + lh * 2;
            const unsigned* Ar = &smem[b][r][0];
            const uint4 q0 = *(const uint4*)&Ar[((c0    ) ^ sw) * 4];
            const uint4 q1 = *(const uint4*)&Ar[((c0 + 1) ^ sw) * 4];
            if (AMODE == 1) {
                uint4 uh, ul;
                uh.x = __builtin_amdgcn_perm(q0.y, q0.x, 0x05040100u);
                uh.y = __builtin_amdgcn_perm(q0.w, q0.z, 0x05040100u);
                uh.z = __builtin_amdgcn_perm(q1.y, q1.x, 0x05040100u);
                uh.w = __builtin_amdgcn_perm(q1.w, q1.z, 0x05040100u);
                ul.x = __builtin_amdgcn_perm(q0.y, q0.x, 0x07060302u);
                ul.y = __builtin_amdgcn_perm(q0.w, q0.z, 0x07060302u);
                ul.z = __builtin_amdgcn_perm(q1.y, q1.x, 0x07060302u);
                ul.w = __builtin_amdgcn_perm(q1.w, q1.z, 0x07060302u);
                ah[tr] = __builtin_bit_cast(f16x8, uh);
                al[tr] = __builtin_bit_cast(f16x8, ul);
            } else {
                const float fv[8] = {
                    __builtin_bit_cast(float, q0.x), __builtin_bit_cast(float, q0.y),
                    __builtin_bit_cast(float, q0.z), __builtin_bit_cast(float, q0.w),
                    __builtin_bit_cast(float, q1.x), __builtin_bit_cast(float, q1.y),
                    __builtin_bit_cast(float, q1.z), __builtin_bit_cast(float, q1.w)};
                #pragma unroll
                for (int j = 0; j < 8; ++j) {
                    const _Float16 h = (_Float16)fv[j];
                    ah[tr][j] = h;
                    al[tr][j] = (_Float16)(fv[j] - (float)h);
                }
            }
        }
    };
    auto MF = [&](const f16x8* ah, const f16x8* al,
                  const f16x8* WH, const f16x8* WL) {
        // per-acc order matches v0 exactly: ah*wh, ah*wl, al*wh
        #pragma unroll
        for (int tr = 0; tr < 2; ++tr)
            #pragma unroll
            for (int tc = 0; tc < 4; ++tc) {
                acc[tr][tc] = __builtin_amdgcn_mfma_f32_32x32x16_f16(ah[tr], WH[tc], acc[tr][tc], 0, 0, 0);
                acc[tr][tc] = __builtin_amdgcn_mfma_f32_32x32x16_f16(ah[tr], WL[tc], acc[tr][tc], 0, 0, 0);
                acc[tr][tc] = __builtin_amdgcn_mfma_f32_32x32x16_f16(al[tr], WH[tc], acc[tr][tc], 0, 0, 0);
            }
    };

    STAGE(0, 0);
    PW(0, WH0, WL0);

    #pragma unroll 1
    for (int t = 0; t < 8; ++t) {
        __syncthreads();                       // drains vmcnt -> buf[t&1] ready
        if (t < 7) STAGE(t + 1, (t + 1) & 1);  // in flight until next barrier
        const int b = t & 1;
        {   // ks = 0 (k-step s = 2t), uses set0; prefetch s+1 -> set1
            if (2 * t + 1 < 16) PW(2 * t + 1, WH1, WL1);
            f16x8 ah[2], al[2];
            LOADA(b, 0, ah, al);
            MF(ah, al, WH0, WL0);
        }
        {   // ks = 1 (s = 2t+1), uses set1; prefetch s+1 -> set0
            if (2 * t + 2 < 16) PW(2 * t + 2, WH0, WL0);
            f16x8 ah[2], al[2];
            LOADA(b, 1, ah, al);
            MF(ah, al, WH1, WL1);
        }
    }
    __syncthreads();   // LDS reads done before red[] aliasing / exit

    // C/D layout (32x32): col = lane&31, row = (reg&3) + 8*(reg>>2) + 4*(lane>>5)

    if (EPI == 0) {
        float* z = (float*)outv;
        #pragma unroll
        for (int tr = 0; tr < 2; ++tr)
            #pragma unroll
            for (int i = 0; i < 16; ++i) {
                const int r  = rh * 64 + tr * 32 + 4 * lh + (i & 3) + 8 * (i >> 2);
                const int gr = bm0 + r;
                if (gr < M) {
                    #pragma unroll
                    for (int tc = 0; tc < 4; ++tc)
                        z[(size_t)gr * 256 + ch * 128 + tc * 32 + l31] = acc[tr][tc][i];
                }
            }
        return;
    }

    {
        float bias[4];
        #pragma unroll
        for (int tc = 0; tc < 4; ++tc)
            bias[tc] = (ch ? bB : bA)[tc * 32 + l31];
        #pragma unroll
        for (int tr = 0; tr < 2; ++tr)
            #pragma unroll
            for (int tc = 0; tc < 4; ++tc)
                #pragma unroll
                for (int i = 0; i < 16; ++i)
                    acc[tr][tc][i] = fmaxf(acc[tr][tc][i] + bias[tc], 0.0f);
    }

    float* red = (float*)smem;

    if (EPI == 1) {
        float ss[2][16];
        #pragma unroll
        for (int tr = 0; tr < 2; ++tr)
            #pragma unroll
            for (int i = 0; i < 16; ++i) {
                float s = 0.f;
                #pragma unroll
                for (int tc = 0; tc < 4; ++tc) s += acc[tr][tc][i] * acc[tr][tc][i];
                #pragma unroll
                for (int m = 1; m < 32; m <<= 1) s += __shfl_xor(s, m);
                ss[tr][i] = s;
            }
        const int j  = l31;
        const int ji = j & 15, jt = j >> 4;
        red[ch * 128 + rh * 64 + jt * 32 + 4 * lh + (ji & 3) + 8 * (ji >> 2)] = ss[jt][ji];
        __syncthreads();

        unsigned* hp = (unsigned*)outv;
        #pragma unroll
        for (int tr = 0; tr < 2; ++tr)
            #pragma unroll
            for (int i = 0; i < 16; ++i) {
                const int rl = rh * 64 + tr * 32 + 4 * lh + (i & 3) + 8 * (i >> 2);
                const float inv = 1.0f / sqrtf(red[rl] + red[128 + rl]);
                const int gr = bm0 + rl;
                if (gr < M) {
                    #pragma unroll
                    for (int tc = 0; tc < 4; ++tc)
                        hp[(size_t)gr * 256 + ch * 128 + tc * 32 + l31] =
                            pack_pair(acc[tr][tc][i] * inv);
                }
            }
        return;
    }

    // EPI == 2: fused head matvec
    {
        float wv[4];
        #pragma unroll
        for (int tc = 0; tc < 4; ++tc) wv[tc] = wd2[ch * 128 + tc * 32 + l31];
        float dd[2][16];
        #pragma unroll
        for (int tr = 0; tr < 2; ++tr)
            #pragma unroll
            for (int i = 0; i < 16; ++i) {
                float s = 0.f;
                #pragma unroll
                for (int tc = 0; tc < 4; ++tc) s += acc[tr][tc][i] * wv[tc];
                #pragma unroll
                for (int m = 1; m < 32; m <<= 1) s += __shfl_xor(s, m);
                dd[tr][i] = s;
            }
        const int j  = l31;
        const int ji = j & 15, jt = j >> 4;
        red[ch * 128 + rh * 64 + jt * 32 + 4 * lh + (ji & 3) + 8 * (ji >> 2)] = dd[jt][ji];
        __syncthreads();
        if (tid < 128) {
            const int gr = bm0 + tid;
            if (gr < M) out1[gr] = red[tid] + red[128 + tid] + bd2[0];
        }
    }
}

// ---- layer-1 GEMM with fused bucket-scatter A3 (extra blocks past gb) ----
__global__ __launch_bounds__(256, 2)
void gemm_l1(const void* __restrict__ Av, const _Float16* __restrict__ wpk,
             const float* __restrict__ bA, const float* __restrict__ bB,
             void* __restrict__ outv, int M, int gb,
             const int* __restrict__ ei, int E, int nb,
             int* __restrict__ gcur, int2* __restrict__ ebuf)
{
    if ((int)blockIdx.x < gb) {
        gemm2_body<0, 1>(Av, wpk, bA, bB, outv, nullptr, nullptr, nullptr, M);
    } else {
        __shared__ int h[NBMAX], cur[NBMAX];
        const int tid = threadIdx.x;
        const int b   = (int)blockIdx.x - gb;       // 0..127
        for (int t = tid; t < nb; t += 256) h[t] = 0;
        __syncthreads();
        const int EB = (E + 127) >> 7;
        const int e0 = b * EB, e1 = min(E, e0 + EB);
        for (int e = e0 + tid; e < e1; e += 256)
            atomicAdd(&h[ei[E + e] >> 8], 1);
        __syncthreads();
        for (int t = tid; t < nb; t += 256)
            cur[t] = atomicAdd(&gcur[t], h[t]);
        __syncthreads();
        for (int e = e0 + tid; e < e1; e += 256) {
            const int d = ei[E + e];
            const int p = atomicAdd(&cur[d >> 8], 1);
            ebuf[p] = make_int2(d, ei[e]);
        }
    }
}

__global__ __launch_bounds__(256, 2)
void gemm_z(const void* __restrict__ Av, const _Float16* __restrict__ wpk,
            void* __restrict__ outv, int M)
{
    gemm2_body<1, 0>(Av, wpk, nullptr, nullptr, outv, nullptr, nullptr, nullptr, M);
}

__global__ __launch_bounds__(256, 2)
void gemm_head(const void* __restrict__ Av, const _Float16* __restrict__ wpk,
               const float* __restrict__ bA, const float* __restrict__ bB,
               const float* __restrict__ wd2, const float* __restrict__ bd2,
               float* __restrict__ out1, int M)
{
    gemm2_body<1, 2>(Av, wpk, bA, bB, nullptr, wd2, bd2, out1, M);
}

// ------------------------- bucket CSR build -------------------------

__global__ __launch_bounds__(256)
void hist_kernel(const int* __restrict__ ei, int E, int nb,
                 int* __restrict__ ghist)
{
    __shared__ int h[NBMAX];
    const int tid = threadIdx.x;
    for (int t = tid; t < nb; t += 256) h[t] = 0;
    __syncthreads();
    const int EB = (E + 127) >> 7;
    const int e0 = (int)blockIdx.x * EB, e1 = min(E, e0 + EB);
    for (int e = e0 + tid; e < e1; e += 256)
        atomicAdd(&h[ei[E + e] >> 8], 1);
    __syncthreads();
    for (int t = tid; t < nb; t += 256)
        if (h[t]) atomicAdd(&ghist[t], h[t]);
}

__global__ __launch_bounds__(512)
void scanb_kernel(const int* __restrict__ ghist, int* __restrict__ gboff,
                  int* __restrict__ gcur, int* __restrict__ rp, int M, int E,
                  int nb)
{
    __shared__ int sm[512];
    const int tid = threadIdx.x;
    const int v = (tid < nb) ? ghist[tid] : 0;
    sm[tid] = v;
    __syncthreads();
    for (int off = 1; off < 512; off <<= 1) {
        int t = (tid >= off) ? sm[tid - off] : 0;
        __syncthreads();
        sm[tid] += t;
        __syncthreads();
    }
    if (tid < nb) {
        const int ex = sm[tid] - v;
        gboff[tid] = ex;
        gcur[tid]  = ex;
    }
    if (tid == 0) { gboff[nb] = E; rp[M] = E; }
}

__global__ __launch_bounds__(256)
void bucket_kernel(const int2* __restrict__ ebuf, const int* __restrict__ gboff,
                   int* __restrict__ rp, int* __restrict__ esrc, int M)
{
    const int b   = (int)blockIdx.x;
    const int tid = threadIdx.x;
    const int base = gboff[b], top = gboff[b + 1];
    const int d0 = b << 8;
    __shared__ int c[256], sm[256], cur[256];
    c[tid] = 0;
    __syncthreads();
    for (int j = base + tid; j < top; j += 256)
        atomicAdd(&c[ebuf[j].x - d0], 1);
    __syncthreads();
    sm[tid] = c[tid];
    __syncthreads();
    for (int off = 1; off < 256; off <<= 1) {
        int t = (tid >= off) ? sm[tid - off] : 0;
        __syncthreads();
        sm[tid] += t;
        __syncthreads();
    }
    const int excl = sm[tid] - c[tid];
    const int d = d0 + tid;
    if (d < M) rp[d] = base + excl;
    cur[tid] = base + excl;
    __syncthreads();
    for (int j = base + tid; j < top; j += 256) {
        const int2 e = ebuf[j];
        const int p = atomicAdd(&cur[e.x - d0], 1);
        esrc[p] = e.y;
    }
}

// ---- finalize: h[v] = l2norm(relu([z1[v]+b2 | segsum(z2[src])+b3])) ----
__global__ __launch_bounds__(256)
void fin_kernel(const float* __restrict__ z, const int* __restrict__ rp,
                const int* __restrict__ esrc,
                const float* __restrict__ b2, const float* __restrict__ b3,
                unsigned* __restrict__ hp, int M)
{
    const int v    = blockIdx.x * 4 + (threadIdx.x >> 6);
    const int lane = threadIdx.x & 63;
    if (v >= M) return;
    const int beg = rp[v], end = rp[v + 1];
    const int deg = end - beg;

    const float2 z1 = *(const float2*)&z[(size_t)v * DIM + lane * 2];
    const float2 c2 = *(const float2*)&b2[lane * 2];
    const float2 c3 = *(const float2*)&b3[lane * 2];

    const float* z2 = z + 128;
    float ax0 = 0.f, ay0 = 0.f, ax1 = 0.f, ay1 = 0.f;
    float ax2 = 0.f, ay2 = 0.f, ax3 = 0.f, ay3 = 0.f;

    for (int base = 0; base < deg; base += 64) {
        const int cnt = min(64, deg - base);
        int myidx = 0;
        if (lane < cnt) myidx = esrc[beg + base + lane];
        int j = 0;
        for (; j + 3 < cnt; j += 4) {
            const int s0 = __builtin_amdgcn_readlane(myidx, j);
            const int s1 = __builtin_amdgcn_readlane(myidx, j + 1);
            const int s2 = __builtin_amdgcn_readlane(myidx, j + 2);
            const int s3 = __builtin_amdgcn_readlane(myidx, j + 3);
            const float2 g0 = *(const float2*)&z2[(size_t)s0 * DIM + lane * 2];
            const float2 g1 = *(const float2*)&z2[(size_t)s1 * DIM + lane * 2];
            const float2 g2 = *(const float2*)&z2[(size_t)s2 * DIM + lane * 2];
            const float2 g3 = *(const float2*)&z2[(size_t)s3 * DIM + lane * 2];
            ax0 += g0.x; ay0 += g0.y;
            ax1 += g1.x; ay1 += g1.y;
            ax2 += g2.x; ay2 += g2.y;
            ax3 += g3.x; ay3 += g3.y;
        }
        for (; j < cnt; ++j) {
            const int s0 = __builtin_amdgcn_readlane(myidx, j);
            const float2 g0 = *(const float2*)&z2[(size_t)s0 * DIM + lane * 2];
            ax0 += g0.x; ay0 += g0.y;
        }
    }
    const float sx = (ax0 + ax1) + (ax2 + ax3);
    const float sy = (ay0 + ay1) + (ay2 + ay3);

    const float u1x = fmaxf(z1.x + c2.x, 0.f), u1y = fmaxf(z1.y + c2.y, 0.f);
    const float u2x = fmaxf(sx + c3.x, 0.f),  u2y = fmaxf(sy + c3.y, 0.f);

    float ss = u1x * u1x + u1y * u1y + u2x * u2x + u2y * u2y;
    #pragma unroll
    for (int off = 32; off > 0; off >>= 1) ss += __shfl_xor(ss, off);
    const float inv = 1.0f / sqrtf(ss);

    uint2 p1; p1.x = pack_pair(u1x * inv); p1.y = pack_pair(u1y * inv);
    uint2 p2; p2.x = pack_pair(u2x * inv); p2.y = pack_pair(u2y * inv);
    *(uint2*)&hp[(size_t)v * DIM + lane * 2]       = p1;
    *(uint2*)&hp[(size_t)v * DIM + 128 + lane * 2] = p2;
}

// ------------------------- launch -------------------------

extern "C" void kernel_launch(void* const* d_in, const int* in_sizes, int n_in,
                              void* d_out, int out_size, void* d_ws, size_t ws_size,
                              hipStream_t stream)
{
    const float* x   = (const float*)d_in[0];
    const int*   ei  = (const int*)d_in[1];
    const float* W1  = (const float*)d_in[2];
    const float* b1  = (const float*)d_in[3];
    const float* W2  = (const float*)d_in[4];
    const float* b2  = (const float*)d_in[5];
    const float* W3  = (const float*)d_in[6];
    const float* b3  = (const float*)d_in[7];
    const float* Wd1 = (const float*)d_in[8];
    const float* bd1 = (const float*)d_in[9];
    const float* Wd2 = (const float*)d_in[10];
    const float* bd2 = (const float*)d_in[11];
    float* out = (float*)d_out;

    const int M = in_sizes[0] / DIM;   // 100000
    const int E = in_sizes[1] / 2;     // 1600000
    const int nb = (M + 255) >> 8;     // 391 buckets of 256 dsts

    unsigned* hp  = (unsigned*)d_ws;                  // M*256 u32 (hi,lo) pairs
    float*    z   = (float*)(hp + (size_t)M * DIM);   // M*256 f32
    int*   rp     = (int*)(z + (size_t)M * DIM);      // M+1
    int*   esrc   = rp + (M + 1);                     // E
    int*   ghist  = esrc + E;                         // nb
    int*   gboff  = ghist + nb;                       // nb+1
    int*   gcur   = gboff + nb + 1;                   // nb
    int2*  ebuf   = (int2*)z;                         // aliases z (disjoint in time)

    // packed weights (256 KB each), 256-B aligned
    size_t woff = (size_t)((char*)(gcur + nb) - (char*)d_ws);
    woff = (woff + 255) & ~(size_t)255;
    _Float16* wpk1 = (_Float16*)((char*)d_ws + woff);
    _Float16* wpk2 = wpk1 + 131072;
    _Float16* wpkd = wpk2 + 131072;

    hipMemsetAsync(ghist, 0, sizeof(int) * nb, stream);

    const int gb  = (M + BM - 1) / BM;       // 782 gemm blocks
    const int fb  = (M + 3) / 4;             // fin: 4 nodes (waves) per block

    // one-time fragment-major (hi,lo) pack of W1, [W2;W3], Wd1
    pack_w_kernel<<<192, 256, 0, stream>>>(
        W1, W1 + 128 * DIM, W2, W3, Wd1, Wd1 + 128 * DIM, wpk1, wpk2, wpkd);

    // bucket histogram + scan (cheap, coalesced)
    hist_kernel<<<128, 256, 0, stream>>>(ei, E, nb, ghist);
    scanb_kernel<<<1, 512, 0, stream>>>(ghist, gboff, gcur, rp, M, E, nb);

    // layer-1 GEMM + bucket-scatter A3 (overlapped in one grid)
    gemm_l1<<<gb + 128, 256, 0, stream>>>(
        x, wpk1, b1, b1 + 128, hp, M, gb, ei, E, nb, gcur, ebuf);

    // per-bucket CSR finalize: rp + esrc
    bucket_kernel<<<nb, 256, 0, stream>>>(ebuf, gboff, rp, esrc, M);

    // z GEMM #1, finalize
    gemm_z<<<gb, 256, 0, stream>>>(hp, wpk2, z, M);
    fin_kernel<<<fb, 256, 0, stream>>>(z, rp, esrc, b2, b3, hp, M);

    // z GEMM #2, finalize
    gemm_z<<<gb, 256, 0, stream>>>(hp, wpk2, z, M);
    fin_kernel<<<fb, 256, 0, stream>>>(z, rp, esrc, b2, b3, hp, M);

    // head: out = relu(h @ Wd1^T + bd1) @ Wd2^T + bd2
    gemm_head<<<gb, 256, 0, stream>>>(
        hp, wpkd, bd1, bd1 + 128, Wd2, bd2, out, M);
}

// Round 5
// 712.163 us; speedup vs baseline: 1.1854x; 1.0063x over previous
//
#include <hip/hip_runtime.h>
#include <math.h>

// ---------------------------------------------------------------------------
// DQNNet GNN, f16x3 split-precision MFMA GEMMs (error ~2^-22, fp32-equivalent).
//   h = l2norm(relu(x @ W1^T + b1))            [gemm_l1, + fused bucket-scatter]
//   2x: z = h @ [W2;W3]^T                      [gemm_z]
//       h = l2norm(relu([z1+b2 | segsum(z2[src])+b3]))   [fin]
//   out = relu(h @ Wd1^T + bd1) @ Wd2^T + bd2  [gemm_head, matvec fused]
//
// v6: dispatch-level overlap (GEMM core unchanged from v5).
//   - Edge-scatter tail blocks now run FIRST in gemm_l1's grid (blockIdx
//     0..tb-1), so scatter overlaps the gemm stream instead of appending
//     serially (blocks dispatch in blockIdx order).
//   - hist_kernel fused into the pack_w dispatch (independent inputs).
//   GEMM: A staged via global_load_lds w=16, double-buffered, source-addr
//   swizzle; W packed fragment-major hi/lo, register-prefetched from L2.
// h stored as (hi,lo) f16 pairs packed in u32 (same bytes as fp32).
// ---------------------------------------------------------------------------

typedef _Float16 f16x8 __attribute__((ext_vector_type(8)));
typedef float    f32x16 __attribute__((ext_vector_type(16)));

constexpr int DIM = 256;
constexpr int BM  = 128;
constexpr int NBMAX = 392; // max buckets (256 dsts each): M<=100352
constexpr int TB   = 192;  // scatter tail blocks (run first)

__device__ __forceinline__ unsigned pack_pair(float v) {
    _Float16 hi = (_Float16)v;
    _Float16 lo = (_Float16)(v - (float)hi);
    return (unsigned)__builtin_bit_cast(unsigned short, hi)
         | ((unsigned)__builtin_bit_cast(unsigned short, lo) << 16);
}

__device__ __forceinline__ void glds16(const void* g, void* l) {
    __builtin_amdgcn_global_load_lds(
        (const __attribute__((address_space(1))) unsigned*)g,
        (__attribute__((address_space(3))) unsigned*)l, 16, 0, 0);
}

// ---- fused one-time W pack (blocks 0..191) + edge histogram (192..319) ----
// pack dst layout: frag = (((hl*8 + t)*2 + ks)*8 + nt), slot = frag*64 + lane,
// 8 f16 per slot: W[n = nt*32 + (lane&31)][k = t*32 + ks*16 + (lane>>5)*8 + j]
__global__ __launch_bounds__(256)
void pack_hist_kernel(const float* __restrict__ WA0, const float* __restrict__ WB0,
                      const float* __restrict__ WA1, const float* __restrict__ WB1,
                      const float* __restrict__ WA2, const float* __restrict__ WB2,
                      _Float16* __restrict__ d0, _Float16* __restrict__ d1,
                      _Float16* __restrict__ d2,
                      const int* __restrict__ ei, int E, int nb,
                      int* __restrict__ ghist)
{
    if ((int)blockIdx.x < 192) {
        const int layer = (int)blockIdx.x >> 6;
        const int tid   = ((int)blockIdx.x & 63) * 256 + threadIdx.x;  // 0..16383
        const float* WA = layer == 0 ? WA0 : layer == 1 ? WA1 : WA2;
        const float* WB = layer == 0 ? WB0 : layer == 1 ? WB1 : WB2;
        _Float16* dst   = layer == 0 ? d0  : layer == 1 ? d1  : d2;

        const int lane = tid & 63;
        const int frag = tid >> 6;               // 0..255
        const int nt = frag & 7;
        const int ks = (frag >> 3) & 1;
        const int t  = (frag >> 4) & 7;
        const int hl = frag >> 7;
        const int n  = nt * 32 + (lane & 31);
        const int k0 = t * 32 + ks * 16 + (lane >> 5) * 8;
        const float* src = (n < 128) ? &WA[(size_t)n * 256]
                                     : &WB[(size_t)(n - 128) * 256];
        f16x8 o;
        #pragma unroll
        for (int j = 0; j < 8; ++j) {
            const float v = src[k0 + j];
            const _Float16 h = (_Float16)v;
            o[j] = hl ? (_Float16)(v - (float)h) : h;
        }
        *(f16x8*)&dst[(size_t)tid * 8] = o;
    } else {
        __shared__ int h[NBMAX];
        const int tid = threadIdx.x;
        const int b   = (int)blockIdx.x - 192;   // 0..127
        for (int t = tid; t < nb; t += 256) h[t] = 0;
        __syncthreads();
        const int EB = (E + 127) >> 7;
        const int e0 = b * EB, e1 = min(E, e0 + EB);
        for (int e = e0 + tid; e < e1; e += 256)
            atomicAdd(&h[ei[E + e] >> 8], 1);
        __syncthreads();
        for (int t = tid; t < nb; t += 256)
            if (h[t]) atomicAdd(&ghist[t], h[t]);
    }
}

// ---------------------------------------------------------------------------
// GEMM body. BM=128 rows/block, 4 waves: rh = w>>1 (64-row half),
// ch = w&1 (128-col half). Per wave: acc[2][4] f32x16 = 64x128 output.
// AMODE: 0 = A is fp32 (cvt-split at read); 1 = A is (hi,lo)-pair u32 (perm).
// EPI:   0 = raw fp32 z; 1 = bias+relu+l2norm -> pair; 2 = bias+relu+matvec.
// ---------------------------------------------------------------------------
template <int AMODE, int EPI>
__device__ __forceinline__
void gemm2_body(const void* __restrict__ Av, const _Float16* __restrict__ Wpk,
                const float* __restrict__ bA, const float* __restrict__ bB,
                void* __restrict__ outv,
                const float* __restrict__ wd2, const float* __restrict__ bd2,
                float* __restrict__ out1, int M, int bm0)
{
    // A tile double buffer: [buf][row 0..127][32 u32 = 8 chunks of 16B]
    __shared__ __align__(16) unsigned smem[2][128][32];   // 32 KB

    const int tid  = threadIdx.x;
    const int lane = tid & 63;
    const int w    = tid >> 6;
    const int rh   = w >> 1;
    const int ch   = w & 1;
    const int l31  = lane & 31;
    const int lh   = lane >> 5;

    // W: fragment-major; hi at base, lo at +128 frags (131072 B);
    // frag byte = s*8192 + tc*1024 + (ch*4*64 + lane)*16.
    const char* wh_p = (const char*)Wpk + (size_t)(ch * 4 * 64 + lane) * 16;
    const char* wl_p = wh_p + 131072;

    // staging geometry: wave w stages rows [w*32, w*32+32), 4 instrs of
    // 1KB (8 rows x 8 chunks); lane -> (row = +lane>>3, chunk = lane&7).
    const int srb  = w * 32;
    const int srow = lane >> 3;
    const int scp  = lane & 7;

    f32x16 acc[2][4];
    #pragma unroll
    for (int tr = 0; tr < 2; ++tr)
        #pragma unroll
        for (int tc = 0; tc < 4; ++tc)
            #pragma unroll
            for (int i = 0; i < 16; ++i) acc[tr][tc][i] = 0.0f;

    f16x8 WH0[4], WL0[4], WH1[4], WL1[4];

    auto STAGE = [&](int t, int b) {
        #pragma unroll
        for (int i = 0; i < 4; ++i) {
            const int r  = srb + i * 8 + srow;
            const int rg = min(bm0 + r, M - 1);          // clamp; stores guarded
            const int cl = scp ^ (r & 7);                // source pre-swizzle
            glds16((const char*)Av + (size_t)rg * 1024 + t * 128 + cl * 16,
                   (void*)&smem[b][srb + i * 8][0]);     // uniform base +lane*16
        }
    };
    auto PW = [&](int s, f16x8* WH, f16x8* WL) {
        #pragma unroll
        for (int tc = 0; tc < 4; ++tc) {
            WH[tc] = *(const f16x8*)(wh_p + (size_t)s * 8192 + tc * 1024);
            WL[tc] = *(const f16x8*)(wl_p + (size_t)s * 8192 + tc * 1024);
        }
    };
    auto LOADA = [&](int b, int ks, f16x8* ah, f16x8* al) {
        #pragma unroll
        for (int tr = 0; tr < 2; ++tr) {
            const int r  = rh * 64 + tr * 32 + l31;
            const int sw = r & 7;
            const int c0 = ks * 4 + lh * 2;
            const unsigned* Ar = &smem[b][r][0];
            const uint4 q0 = *(const uint4*)&Ar[((c0    ) ^ sw) * 4];
            const uint4 q1 = *(const uint4*)&Ar[((c0 + 1) ^ sw) * 4];
            if (AMODE == 1) {
                uint4 uh, ul;
                uh.x = __builtin_amdgcn_perm(q0.y, q0.x, 0x05040100u);
                uh.y = __builtin_amdgcn_perm(q0.w, q0.z, 0x05040100u);
                uh.z = __builtin_amdgcn_perm(q1.y, q1.x, 0x05040100u);
                uh.w = __builtin_amdgcn_perm(q1.w, q1.z, 0x05040100u);
                ul.x = __builtin_amdgcn_perm(q0.y, q0.x, 0x07060302u);
                ul.y = __builtin_amdgcn_perm(q0.w, q0.z, 0x07060302u);
                ul.z = __builtin_amdgcn_perm(q1.y, q1.x, 0x07060302u);
                ul.w = __builtin_amdgcn_perm(q1.w, q1.z, 0x07060302u);
                ah[tr] = __builtin_bit_cast(f16x8, uh);
                al[tr] = __builtin_bit_cast(f16x8, ul);
            } else {
                const float fv[8] = {
                    __builtin_bit_cast(float, q0.x), __builtin_bit_cast(float, q0.y),
                    __builtin_bit_cast(float, q0.z), __builtin_bit_cast(float, q0.w),
                    __builtin_bit_cast(float, q1.x), __builtin_bit_cast(float, q1.y),
                    __builtin_bit_cast(float, q1.z), __builtin_bit_cast(float, q1.w)};
                #pragma unroll
                for (int j = 0; j < 8; ++j) {
                    const _Float16 h = (_Float16)fv[j];
                    ah[tr][j] = h;
                    al[tr][j] = (_Float16)(fv[j] - (float)h);
                }
            }
        }
    };
    auto MF = [&](const f16x8* ah, const f16x8* al,
                  const f16x8* WH, const f16x8* WL) {
        // per-acc order matches v0 exactly: ah*wh, ah*wl, al*wh
        #pragma unroll
        for (int tr = 0; tr < 2; ++tr)
            #pragma unroll
            for (int tc = 0; tc < 4; ++tc) {
                acc[tr][tc] = __builtin_amdgcn_mfma_f32_32x32x16_f16(ah[tr], WH[tc], acc[tr][tc], 0, 0, 0);
                acc[tr][tc] = __builtin_amdgcn_mfma_f32_32x32x16_f16(ah[tr], WL[tc], acc[tr][tc], 0, 0, 0);
                acc[tr][tc] = __builtin_amdgcn_mfma_f32_32x32x16_f16(al[tr], WH[tc], acc[tr][tc], 0, 0, 0);
            }
    };

    STAGE(0, 0);
    PW(0, WH0, WL0);

    #pragma unroll 1
    for (int t = 0; t < 8; ++t) {
        __syncthreads();                       // drains vmcnt -> buf[t&1] ready
        if (t < 7) STAGE(t + 1, (t + 1) & 1);  // in flight until next barrier
        const int b = t & 1;
        {   // ks = 0 (k-step s = 2t), uses set0; prefetch s+1 -> set1
            if (2 * t + 1 < 16) PW(2 * t + 1, WH1, WL1);
            f16x8 ah[2], al[2];
            LOADA(b, 0, ah, al);
            MF(ah, al, WH0, WL0);
        }
        {   // ks = 1 (s = 2t+1), uses set1; prefetch s+1 -> set0
            if (2 * t + 2 < 16) PW(2 * t + 2, WH0, WL0);
            f16x8 ah[2], al[2];
            LOADA(b, 1, ah, al);
            MF(ah, al, WH1, WL1);
        }
    }
    __syncthreads();   // LDS reads done before red[] aliasing / exit

    // C/D layout (32x32): col = lane&31, row = (reg&3) + 8*(reg>>2) + 4*(lane>>5)

    if (EPI == 0) {
        float* z = (float*)outv;
        #pragma unroll
        for (int tr = 0; tr < 2; ++tr)
            #pragma unroll
            for (int i = 0; i < 16; ++i) {
                const int r  = rh * 64 + tr * 32 + 4 * lh + (i & 3) + 8 * (i >> 2);
                const int gr = bm0 + r;
                if (gr < M) {
                    #pragma unroll
                    for (int tc = 0; tc < 4; ++tc)
                        z[(size_t)gr * 256 + ch * 128 + tc * 32 + l31] = acc[tr][tc][i];
                }
            }
        return;
    }

    {
        float bias[4];
        #pragma unroll
        for (int tc = 0; tc < 4; ++tc)
            bias[tc] = (ch ? bB : bA)[tc * 32 + l31];
        #pragma unroll
        for (int tr = 0; tr < 2; ++tr)
            #pragma unroll
            for (int tc = 0; tc < 4; ++tc)
                #pragma unroll
                for (int i = 0; i < 16; ++i)
                    acc[tr][tc][i] = fmaxf(acc[tr][tc][i] + bias[tc], 0.0f);
    }

    float* red = (float*)smem;

    if (EPI == 1) {
        float ss[2][16];
        #pragma unroll
        for (int tr = 0; tr < 2; ++tr)
            #pragma unroll
            for (int i = 0; i < 16; ++i) {
                float s = 0.f;
                #pragma unroll
                for (int tc = 0; tc < 4; ++tc) s += acc[tr][tc][i] * acc[tr][tc][i];
                #pragma unroll
                for (int m = 1; m < 32; m <<= 1) s += __shfl_xor(s, m);
                ss[tr][i] = s;
            }
        const int j  = l31;
        const int ji = j & 15, jt = j >> 4;
        red[ch * 128 + rh * 64 + jt * 32 + 4 * lh + (ji & 3) + 8 * (ji >> 2)] = ss[jt][ji];
        __syncthreads();

        unsigned* hp = (unsigned*)outv;
        #pragma unroll
        for (int tr = 0; tr < 2; ++tr)
            #pragma unroll
            for (int i = 0; i < 16; ++i) {
                const int rl = rh * 64 + tr * 32 + 4 * lh + (i & 3) + 8 * (i >> 2);
                const float inv = 1.0f / sqrtf(red[rl] + red[128 + rl]);
                const int gr = bm0 + rl;
                if (gr < M) {
                    #pragma unroll
                    for (int tc = 0; tc < 4; ++tc)
                        hp[(size_t)gr * 256 + ch * 128 + tc * 32 + l31] =
                            pack_pair(acc[tr][tc][i] * inv);
                }
            }
        return;
    }

    // EPI == 2: fused head matvec
    {
        float wv[4];
        #pragma unroll
        for (int tc = 0; tc < 4; ++tc) wv[tc] = wd2[ch * 128 + tc * 32 + l31];
        float dd[2][16];
        #pragma unroll
        for (int tr = 0; tr < 2; ++tr)
            #pragma unroll
            for (int i = 0; i < 16; ++i) {
                float s = 0.f;
                #pragma unroll
                for (int tc = 0; tc < 4; ++tc) s += acc[tr][tc][i] * wv[tc];
                #pragma unroll
                for (int m = 1; m < 32; m <<= 1) s += __shfl_xor(s, m);
                dd[tr][i] = s;
            }
        const int j  = l31;
        const int ji = j & 15, jt = j >> 4;
        red[ch * 128 + rh * 64 + jt * 32 + 4 * lh + (ji & 3) + 8 * (ji >> 2)] = dd[jt][ji];
        __syncthreads();
        if (tid < 128) {
            const int gr = bm0 + tid;
            if (gr < M) out1[gr] = red[tid] + red[128 + tid] + bd2[0];
        }
    }
}

// ---- layer-1 GEMM with fused bucket-scatter (tail blocks FIRST) ----
// Blocks 0..TB-1: bucketize edges into ebuf as per-(block,bucket) contiguous
// runs (coalesced reads, LDS-local atomics, TB*nb global atomics total).
// Blocks TB..TB+gb-1: the GEMM.
__global__ __launch_bounds__(256, 2)
void gemm_l1(const void* __restrict__ Av, const _Float16* __restrict__ wpk,
             const float* __restrict__ bA, const float* __restrict__ bB,
             void* __restrict__ outv, int M,
             const int* __restrict__ ei, int E, int nb,
             int* __restrict__ gcur, int2* __restrict__ ebuf)
{
    if ((int)blockIdx.x >= TB) {
        gemm2_body<0, 1>(Av, wpk, bA, bB, outv, nullptr, nullptr, nullptr, M,
                         ((int)blockIdx.x - TB) * BM);
    } else {
        __shared__ int h[NBMAX], cur[NBMAX];
        const int tid = threadIdx.x;
        const int b   = (int)blockIdx.x;            // 0..TB-1
        for (int t = tid; t < nb; t += 256) h[t] = 0;
        __syncthreads();
        const int EB = (E + TB - 1) / TB;
        const int e0 = b * EB, e1 = min(E, e0 + EB);
        for (int e = e0 + tid; e < e1; e += 256)
            atomicAdd(&h[ei[E + e] >> 8], 1);
        __syncthreads();
        for (int t = tid; t < nb; t += 256)
            cur[t] = atomicAdd(&gcur[t], h[t]);
        __syncthreads();
        for (int e = e0 + tid; e < e1; e += 256) {
            const int d = ei[E + e];
            const int p = atomicAdd(&cur[d >> 8], 1);
            ebuf[p] = make_int2(d, ei[e]);
        }
    }
}

__global__ __launch_bounds__(256, 2)
void gemm_z(const void* __restrict__ Av, const _Float16* __restrict__ wpk,
            void* __restrict__ outv, int M)
{
    gemm2_body<1, 0>(Av, wpk, nullptr, nullptr, outv, nullptr, nullptr, nullptr,
                     M, (int)blockIdx.x * BM);
}

__global__ __launch_bounds__(256, 2)
void gemm_head(const void* __restrict__ Av, const _Float16* __restrict__ wpk,
               const float* __restrict__ bA, const float* __restrict__ bB,
               const float* __restrict__ wd2, const float* __restrict__ bd2,
               float* __restrict__ out1, int M)
{
    gemm2_body<1, 2>(Av, wpk, bA, bB, nullptr, wd2, bd2, out1, M,
                     (int)blockIdx.x * BM);
}

// ------------------------- bucket CSR build -------------------------

__global__ __launch_bounds__(512)
void scanb_kernel(const int* __restrict__ ghist, int* __restrict__ gboff,
                  int* __restrict__ gcur, int* __restrict__ rp, int M, int E,
                  int nb)
{
    __shared__ int sm[512];
    const int tid = threadIdx.x;
    const int v = (tid < nb) ? ghist[tid] : 0;
    sm[tid] = v;
    __syncthreads();
    for (int off = 1; off < 512; off <<= 1) {
        int t = (tid >= off) ? sm[tid - off] : 0;
        __syncthreads();
        sm[tid] += t;
        __syncthreads();
    }
    if (tid < nb) {
        const int ex = sm[tid] - v;
        gboff[tid] = ex;
        gcur[tid]  = ex;
    }
    if (tid == 0) { gboff[nb] = E; rp[M] = E; }
}

__global__ __launch_bounds__(256)
void bucket_kernel(const int2* __restrict__ ebuf, const int* __restrict__ gboff,
                   int* __restrict__ rp, int* __restrict__ esrc, int M)
{
    const int b   = (int)blockIdx.x;
    const int tid = threadIdx.x;
    const int base = gboff[b], top = gboff[b + 1];
    const int d0 = b << 8;
    __shared__ int c[256], sm[256], cur[256];
    c[tid] = 0;
    __syncthreads();
    for (int j = base + tid; j < top; j += 256)
        atomicAdd(&c[ebuf[j].x - d0], 1);
    __syncthreads();
    sm[tid] = c[tid];
    __syncthreads();
    for (int off = 1; off < 256; off <<= 1) {
        int t = (tid >= off) ? sm[tid - off] : 0;
        __syncthreads();
        sm[tid] += t;
        __syncthreads();
    }
    const int excl = sm[tid] - c[tid];
    const int d = d0 + tid;
    if (d < M) rp[d] = base + excl;
    cur[tid] = base + excl;
    __syncthreads();
    for (int j = base + tid; j < top; j += 256) {
        const int2 e = ebuf[j];
        const int p = atomicAdd(&cur[e.x - d0], 1);
        esrc[p] = e.y;
    }
}

// ---- finalize: h[v] = l2norm(relu([z1[v]+b2 | segsum(z2[src])+b3])) ----
__global__ __launch_bounds__(256)
void fin_kernel(const float* __restrict__ z, const int* __restrict__ rp,
                const int* __restrict__ esrc,
                const float* __restrict__ b2, const float* __restrict__ b3,
                unsigned* __restrict__ hp, int M)
{
    const int v    = blockIdx.x * 4 + (threadIdx.x >> 6);
    const int lane = threadIdx.x & 63;
    if (v >= M) return;
    const int beg = rp[v], end = rp[v + 1];
    const int deg = end - beg;

    const float2 z1 = *(const float2*)&z[(size_t)v * DIM + lane * 2];
    const float2 c2 = *(const float2*)&b2[lane * 2];
    const float2 c3 = *(const float2*)&b3[lane * 2];

    const float* z2 = z + 128;
    float ax0 = 0.f, ay0 = 0.f, ax1 = 0.f, ay1 = 0.f;
    float ax2 = 0.f, ay2 = 0.f, ax3 = 0.f, ay3 = 0.f;

    for (int base = 0; base < deg; base += 64) {
        const int cnt = min(64, deg - base);
        int myidx = 0;
        if (lane < cnt) myidx = esrc[beg + base + lane];
        int j = 0;
        for (; j + 3 < cnt; j += 4) {
            const int s0 = __builtin_amdgcn_readlane(myidx, j);
            const int s1 = __builtin_amdgcn_readlane(myidx, j + 1);
            const int s2 = __builtin_amdgcn_readlane(myidx, j + 2);
            const int s3 = __builtin_amdgcn_readlane(myidx, j + 3);
            const float2 g0 = *(const float2*)&z2[(size_t)s0 * DIM + lane * 2];
            const float2 g1 = *(const float2*)&z2[(size_t)s1 * DIM + lane * 2];
            const float2 g2 = *(const float2*)&z2[(size_t)s2 * DIM + lane * 2];
            const float2 g3 = *(const float2*)&z2[(size_t)s3 * DIM + lane * 2];
            ax0 += g0.x; ay0 += g0.y;
            ax1 += g1.x; ay1 += g1.y;
            ax2 += g2.x; ay2 += g2.y;
            ax3 += g3.x; ay3 += g3.y;
        }
        for (; j < cnt; ++j) {
            const int s0 = __builtin_amdgcn_readlane(myidx, j);
            const float2 g0 = *(const float2*)&z2[(size_t)s0 * DIM + lane * 2];
            ax0 += g0.x; ay0 += g0.y;
        }
    }
    const float sx = (ax0 + ax1) + (ax2 + ax3);
    const float sy = (ay0 + ay1) + (ay2 + ay3);

    const float u1x = fmaxf(z1.x + c2.x, 0.f), u1y = fmaxf(z1.y + c2.y, 0.f);
    const float u2x = fmaxf(sx + c3.x, 0.f),  u2y = fmaxf(sy + c3.y, 0.f);

    float ss = u1x * u1x + u1y * u1y + u2x * u2x + u2y * u2y;
    #pragma unroll
    for (int off = 32; off > 0; off >>= 1) ss += __shfl_xor(ss, off);
    const float inv = 1.0f / sqrtf(ss);

    uint2 p1; p1.x = pack_pair(u1x * inv); p1.y = pack_pair(u1y * inv);
    uint2 p2; p2.x = pack_pair(u2x * inv); p2.y = pack_pair(u2y * inv);
    *(uint2*)&hp[(size_t)v * DIM + lane * 2]       = p1;
    *(uint2*)&hp[(size_t)v * DIM + 128 + lane * 2] = p2;
}

// ------------------------- launch -------------------------

extern "C" void kernel_launch(void* const* d_in, const int* in_sizes, int n_in,
                              void* d_out, int out_size, void* d_ws, size_t ws_size,
                              hipStream_t stream)
{
    const float* x   = (const float*)d_in[0];
    const int*   ei  = (const int*)d_in[1];
    const float* W1  = (const float*)d_in[2];
    const float* b1  = (const float*)d_in[3];
    const float* W2  = (const float*)d_in[4];
    const float* b2  = (const float*)d_in[5];
    const float* W3  = (const float*)d_in[6];
    const float* b3  = (const float*)d_in[7];
    const float* Wd1 = (const float*)d_in[8];
    const float* bd1 = (const float*)d_in[9];
    const float* Wd2 = (const float*)d_in[10];
    const float* bd2 = (const float*)d_in[11];
    float* out = (float*)d_out;

    const int M = in_sizes[0] / DIM;   // 100000
    const int E = in_sizes[1] / 2;     // 1600000
    const int nb = (M + 255) >> 8;     // 391 buckets of 256 dsts

    unsigned* hp  = (unsigned*)d_ws;                  // M*256 u32 (hi,lo) pairs
    float*    z   = (float*)(hp + (size_t)M * DIM);   // M*256 f32
    int*   rp     = (int*)(z + (size_t)M * DIM);      // M+1
    int*   esrc   = rp + (M + 1);                     // E
    int*   ghist  = esrc + E;                         // nb
    int*   gboff  = ghist + nb;                       // nb+1
    int*   gcur   = gboff + nb + 1;                   // nb
    int2*  ebuf   = (int2*)z;                         // aliases z (disjoint in time)

    // packed weights (256 KB each), 256-B aligned
    size_t woff = (size_t)((char*)(gcur + nb) - (char*)d_ws);
    woff = (woff + 255) & ~(size_t)255;
    _Float16* wpk1 = (_Float16*)((char*)d_ws + woff);
    _Float16* wpk2 = wpk1 + 131072;
    _Float16* wpkd = wpk2 + 131072;

    hipMemsetAsync(ghist, 0, sizeof(int) * nb, stream);

    const int gb  = (M + BM - 1) / BM;       // 782 gemm blocks
    const int fb  = (M + 3) / 4;             // fin: 4 nodes (waves) per block

    // one-time W pack (blocks 0..191) + edge bucket histogram (192..319)
    pack_hist_kernel<<<320, 256, 0, stream>>>(
        W1, W1 + 128 * DIM, W2, W3, Wd1, Wd1 + 128 * DIM, wpk1, wpk2, wpkd,
        ei, E, nb, ghist);

    // bucket scan -> offsets
    scanb_kernel<<<1, 512, 0, stream>>>(ghist, gboff, gcur, rp, M, E, nb);

    // layer-1 GEMM + bucket-scatter (scatter blocks FIRST -> overlapped)
    gemm_l1<<<TB + gb, 256, 0, stream>>>(
        x, wpk1, b1, b1 + 128, hp, M, ei, E, nb, gcur, ebuf);

    // per-bucket CSR finalize: rp + esrc
    bucket_kernel<<<nb, 256, 0, stream>>>(ebuf, gboff, rp, esrc, M);

    // z GEMM #1, finalize
    gemm_z<<<gb, 256, 0, stream>>>(hp, wpk2, z, M);
    fin_kernel<<<fb, 256, 0, stream>>>(z, rp, esrc, b2, b3, hp, M);

    // z GEMM #2, finalize
    gemm_z<<<gb, 256, 0, stream>>>(hp, wpk2, z, M);
    fin_kernel<<<fb, 256, 0, stream>>>(z, rp, esrc, b2, b3, hp, M);

    // head: out = relu(h @ Wd1^T + bd1) @ Wd2^T + bd2
    gemm_head<<<gb, 256, 0, stream>>>(
        hp, wpkd, bd1, bd1 + 128, Wd2, bd2, out, M);
}

// Round 6
// 702.519 us; speedup vs baseline: 1.2017x; 1.0137x over previous
//
#include <hip/hip_runtime.h>
#include <math.h>

// ---------------------------------------------------------------------------
// DQNNet GNN, f16x3 split-precision MFMA GEMMs (error ~2^-22, fp32-equivalent).
//   h = l2norm(relu(x @ W1^T + b1))            [gemm_l1, + fused bucket-scatter]
//   2x: z = h @ [W2;W3]^T                      [gemm_z]
//       h = l2norm(relu([z1+b2 | segsum(z2[src])+b3]))   [fin]
//   out = relu(h @ Wd1^T + bd1) @ Wd2^T + bd2  [gemm_head, matvec fused]
//
// v7:
//   - GEMM C-write staged through LDS: 4 passes of 32 rows, re-read row-major,
//     uint4 stores with consecutive lanes -> 1KB contiguous per instruction.
//     (v0-v6 wrote 128-B segments -> 2x HBM write amplification, the invariant
//     ~100us GEMM wall across five inner-loop rewrites.)
//   - fin: nontemporal z1/esrc loads + hp stores (streamed once) to keep the
//     51.2MB z2 gather set LLC-resident.
//   GEMM inner loop unchanged from v5/v6 (global_load_lds, swizzle, W-prefetch).
// h stored as (hi,lo) f16 pairs packed in u32 (same bytes as fp32).
// ---------------------------------------------------------------------------

typedef _Float16 f16x8 __attribute__((ext_vector_type(8)));
typedef float    f32x16 __attribute__((ext_vector_type(16)));

constexpr int DIM = 256;
constexpr int BM  = 128;
constexpr int NBMAX = 392; // max buckets (256 dsts each): M<=100352
constexpr int TB   = 192;  // scatter tail blocks (run first)

__device__ __forceinline__ unsigned pack_pair(float v) {
    _Float16 hi = (_Float16)v;
    _Float16 lo = (_Float16)(v - (float)hi);
    return (unsigned)__builtin_bit_cast(unsigned short, hi)
         | ((unsigned)__builtin_bit_cast(unsigned short, lo) << 16);
}

__device__ __forceinline__ void glds16(const void* g, void* l) {
    __builtin_amdgcn_global_load_lds(
        (const __attribute__((address_space(1))) unsigned*)g,
        (__attribute__((address_space(3))) unsigned*)l, 16, 0, 0);
}

__device__ __forceinline__ float2 ntld_f2(const float* p) {
    unsigned long long v =
        __builtin_nontemporal_load((const unsigned long long*)p);
    return __builtin_bit_cast(float2, v);
}

// ---- fused one-time W pack (blocks 0..191) + edge histogram (192..319) ----
// pack dst layout: frag = (((hl*8 + t)*2 + ks)*8 + nt), slot = frag*64 + lane,
// 8 f16 per slot: W[n = nt*32 + (lane&31)][k = t*32 + ks*16 + (lane>>5)*8 + j]
__global__ __launch_bounds__(256)
void pack_hist_kernel(const float* __restrict__ WA0, const float* __restrict__ WB0,
                      const float* __restrict__ WA1, const float* __restrict__ WB1,
                      const float* __restrict__ WA2, const float* __restrict__ WB2,
                      _Float16* __restrict__ d0, _Float16* __restrict__ d1,
                      _Float16* __restrict__ d2,
                      const int* __restrict__ ei, int E, int nb,
                      int* __restrict__ ghist)
{
    if ((int)blockIdx.x < 192) {
        const int layer = (int)blockIdx.x >> 6;
        const int tid   = ((int)blockIdx.x & 63) * 256 + threadIdx.x;  // 0..16383
        const float* WA = layer == 0 ? WA0 : layer == 1 ? WA1 : WA2;
        const float* WB = layer == 0 ? WB0 : layer == 1 ? WB1 : WB2;
        _Float16* dst   = layer == 0 ? d0  : layer == 1 ? d1  : d2;

        const int lane = tid & 63;
        const int frag = tid >> 6;               // 0..255
        const int nt = frag & 7;
        const int ks = (frag >> 3) & 1;
        const int t  = (frag >> 4) & 7;
        const int hl = frag >> 7;
        const int n  = nt * 32 + (lane & 31);
        const int k0 = t * 32 + ks * 16 + (lane >> 5) * 8;
        const float* src = (n < 128) ? &WA[(size_t)n * 256]
                                     : &WB[(size_t)(n - 128) * 256];
        f16x8 o;
        #pragma unroll
        for (int j = 0; j < 8; ++j) {
            const float v = src[k0 + j];
            const _Float16 h = (_Float16)v;
            o[j] = hl ? (_Float16)(v - (float)h) : h;
        }
        *(f16x8*)&dst[(size_t)tid * 8] = o;
    } else {
        __shared__ int h[NBMAX];
        const int tid = threadIdx.x;
        const int b   = (int)blockIdx.x - 192;   // 0..127
        for (int t = tid; t < nb; t += 256) h[t] = 0;
        __syncthreads();
        const int EB = (E + 127) >> 7;
        const int e0 = b * EB, e1 = min(E, e0 + EB);
        for (int e = e0 + tid; e < e1; e += 256)
            atomicAdd(&h[ei[E + e] >> 8], 1);
        __syncthreads();
        for (int t = tid; t < nb; t += 256)
            if (h[t]) atomicAdd(&ghist[t], h[t]);
    }
}

// ---------------------------------------------------------------------------
// GEMM body. BM=128 rows/block, 4 waves: rh = w>>1 (64-row half),
// ch = w&1 (128-col half). Per wave: acc[2][4] f32x16 = 64x128 output.
// AMODE: 0 = A is fp32 (cvt-split at read); 1 = A is (hi,lo)-pair u32 (perm).
// EPI:   0 = raw fp32 z; 1 = bias+relu+l2norm -> pair; 2 = bias+relu+matvec.
// ---------------------------------------------------------------------------
template <int AMODE, int EPI>
__device__ __forceinline__
void gemm2_body(const void* __restrict__ Av, const _Float16* __restrict__ Wpk,
                const float* __restrict__ bA, const float* __restrict__ bB,
                void* __restrict__ outv,
                const float* __restrict__ wd2, const float* __restrict__ bd2,
                float* __restrict__ out1, int M, int bm0)
{
    // A tile double buffer: [buf][row 0..127][32 u32 = 8 chunks of 16B]
    // Also reused as the 32KB epilogue staging buffer / red[].
    __shared__ __align__(16) unsigned smem[2][128][32];   // 32 KB

    const int tid  = threadIdx.x;
    const int lane = tid & 63;
    const int w    = tid >> 6;
    const int rh   = w >> 1;
    const int ch   = w & 1;
    const int l31  = lane & 31;
    const int lh   = lane >> 5;

    // W: fragment-major; hi at base, lo at +128 frags (131072 B);
    // frag byte = s*8192 + tc*1024 + (ch*4*64 + lane)*16.
    const char* wh_p = (const char*)Wpk + (size_t)(ch * 4 * 64 + lane) * 16;
    const char* wl_p = wh_p + 131072;

    // staging geometry: wave w stages rows [w*32, w*32+32), 4 instrs of
    // 1KB (8 rows x 8 chunks); lane -> (row = +lane>>3, chunk = lane&7).
    const int srb  = w * 32;
    const int srow = lane >> 3;
    const int scp  = lane & 7;

    f32x16 acc[2][4];
    #pragma unroll
    for (int tr = 0; tr < 2; ++tr)
        #pragma unroll
        for (int tc = 0; tc < 4; ++tc)
            #pragma unroll
            for (int i = 0; i < 16; ++i) acc[tr][tc][i] = 0.0f;

    f16x8 WH0[4], WL0[4], WH1[4], WL1[4];

    auto STAGE = [&](int t, int b) {
        #pragma unroll
        for (int i = 0; i < 4; ++i) {
            const int r  = srb + i * 8 + srow;
            const int rg = min(bm0 + r, M - 1);          // clamp; stores guarded
            const int cl = scp ^ (r & 7);                // source pre-swizzle
            glds16((const char*)Av + (size_t)rg * 1024 + t * 128 + cl * 16,
                   (void*)&smem[b][srb + i * 8][0]);     // uniform base +lane*16
        }
    };
    auto PW = [&](int s, f16x8* WH, f16x8* WL) {
        #pragma unroll
        for (int tc = 0; tc < 4; ++tc) {
            WH[tc] = *(const f16x8*)(wh_p + (size_t)s * 8192 + tc * 1024);
            WL[tc] = *(const f16x8*)(wl_p + (size_t)s * 8192 + tc * 1024);
        }
    };
    auto LOADA = [&](int b, int ks, f16x8* ah, f16x8* al) {
        #pragma unroll
        for (int tr = 0; tr < 2; ++tr) {
            const int r  = rh * 64 + tr * 32 + l31;
            const int sw = r & 7;
            const int c0 = ks * 4 + lh * 2;
            const unsigned* Ar = &smem[b][r][0];
            const uint4 q0 = *(const uint4*)&Ar[((c0    ) ^ sw) * 4];
            const uint4 q1 = *(const uint4*)&Ar[((c0 + 1) ^ sw) * 4];
            if (AMODE == 1) {
                uint4 uh, ul;
                uh.x = __builtin_amdgcn_perm(q0.y, q0.x, 0x05040100u);
                uh.y = __builtin_amdgcn_perm(q0.w, q0.z, 0x05040100u);
                uh.z = __builtin_amdgcn_perm(q1.y, q1.x, 0x05040100u);
                uh.w = __builtin_amdgcn_perm(q1.w, q1.z, 0x05040100u);
                ul.x = __builtin_amdgcn_perm(q0.y, q0.x, 0x07060302u);
                ul.y = __builtin_amdgcn_perm(q0.w, q0.z, 0x07060302u);
                ul.z = __builtin_amdgcn_perm(q1.y, q1.x, 0x07060302u);
                ul.w = __builtin_amdgcn_perm(q1.w, q1.z, 0x07060302u);
                ah[tr] = __builtin_bit_cast(f16x8, uh);
                al[tr] = __builtin_bit_cast(f16x8, ul);
            } else {
                const float fv[8] = {
                    __builtin_bit_cast(float, q0.x), __builtin_bit_cast(float, q0.y),
                    __builtin_bit_cast(float, q0.z), __builtin_bit_cast(float, q0.w),
                    __builtin_bit_cast(float, q1.x), __builtin_bit_cast(float, q1.y),
                    __builtin_bit_cast(float, q1.z), __builtin_bit_cast(float, q1.w)};
                #pragma unroll
                for (int j = 0; j < 8; ++j) {
                    const _Float16 h = (_Float16)fv[j];
                    ah[tr][j] = h;
                    al[tr][j] = (_Float16)(fv[j] - (float)h);
                }
            }
        }
    };
    auto MF = [&](const f16x8* ah, const f16x8* al,
                  const f16x8* WH, const f16x8* WL) {
        // per-acc order matches v0 exactly: ah*wh, ah*wl, al*wh
        #pragma unroll
        for (int tr = 0; tr < 2; ++tr)
            #pragma unroll
            for (int tc = 0; tc < 4; ++tc) {
                acc[tr][tc] = __builtin_amdgcn_mfma_f32_32x32x16_f16(ah[tr], WH[tc], acc[tr][tc], 0, 0, 0);
                acc[tr][tc] = __builtin_amdgcn_mfma_f32_32x32x16_f16(ah[tr], WL[tc], acc[tr][tc], 0, 0, 0);
                acc[tr][tc] = __builtin_amdgcn_mfma_f32_32x32x16_f16(al[tr], WH[tc], acc[tr][tc], 0, 0, 0);
            }
    };

    STAGE(0, 0);
    PW(0, WH0, WL0);

    #pragma unroll 1
    for (int t = 0; t < 8; ++t) {
        __syncthreads();                       // drains vmcnt -> buf[t&1] ready
        if (t < 7) STAGE(t + 1, (t + 1) & 1);  // in flight until next barrier
        const int b = t & 1;
        {   // ks = 0 (k-step s = 2t), uses set0; prefetch s+1 -> set1
            if (2 * t + 1 < 16) PW(2 * t + 1, WH1, WL1);
            f16x8 ah[2], al[2];
            LOADA(b, 0, ah, al);
            MF(ah, al, WH0, WL0);
        }
        {   // ks = 1 (s = 2t+1), uses set1; prefetch s+1 -> set0
            if (2 * t + 2 < 16) PW(2 * t + 2, WH0, WL0);
            f16x8 ah[2], al[2];
            LOADA(b, 1, ah, al);
            MF(ah, al, WH1, WL1);
        }
    }
    __syncthreads();   // LDS reads done before epilogue reuses smem

    // C/D layout (32x32): col = lane&31, row = (reg&3) + 8*(reg>>2) + 4*(lane>>5)

    float* red = (float*)smem;

    if (EPI != 0) {   // bias + relu
        float bias[4];
        #pragma unroll
        for (int tc = 0; tc < 4; ++tc)
            bias[tc] = (ch ? bB : bA)[tc * 32 + l31];
        #pragma unroll
        for (int tr = 0; tr < 2; ++tr)
            #pragma unroll
            for (int tc = 0; tc < 4; ++tc)
                #pragma unroll
                for (int i = 0; i < 16; ++i)
                    acc[tr][tc][i] = fmaxf(acc[tr][tc][i] + bias[tc], 0.0f);
    }

    if (EPI == 1) {   // l2norm factors, then pack into acc in place
        float ss[2][16];
        #pragma unroll
        for (int tr = 0; tr < 2; ++tr)
            #pragma unroll
            for (int i = 0; i < 16; ++i) {
                float s = 0.f;
                #pragma unroll
                for (int tc = 0; tc < 4; ++tc) s += acc[tr][tc][i] * acc[tr][tc][i];
                #pragma unroll
                for (int m = 1; m < 32; m <<= 1) s += __shfl_xor(s, m);
                ss[tr][i] = s;
            }
        const int j  = l31;
        const int ji = j & 15, jt = j >> 4;
        red[ch * 128 + rh * 64 + jt * 32 + 4 * lh + (ji & 3) + 8 * (ji >> 2)] = ss[jt][ji];
        __syncthreads();
        #pragma unroll
        for (int tr = 0; tr < 2; ++tr)
            #pragma unroll
            for (int i = 0; i < 16; ++i) {
                const int rl = rh * 64 + tr * 32 + 4 * lh + (i & 3) + 8 * (i >> 2);
                const float inv = 1.0f / sqrtf(red[rl] + red[128 + rl]);
                #pragma unroll
                for (int tc = 0; tc < 4; ++tc)
                    acc[tr][tc][i] = __builtin_bit_cast(float,
                        pack_pair(acc[tr][tc][i] * inv));
            }
        // pass loop's first barrier separates red[] reads from LDS overwrite
    }

    if (EPI == 0 || EPI == 1) {
        // staged coalesced C-write: 4 passes of 32 rows through 32KB LDS;
        // final stores are 16B/lane, wave-contiguous (1KB per instruction).
        float* lds = (float*)smem;
        unsigned* outu = (unsigned*)outv;
        #pragma unroll
        for (int p = 0; p < 4; ++p) {
            __syncthreads();               // prev pass consumed / red[] done
            if (rh == (p >> 1)) {
                const int tr = p & 1;
                #pragma unroll
                for (int i = 0; i < 16; ++i) {
                    const int ro = 4 * lh + (i & 3) + 8 * (i >> 2);   // 0..31
                    #pragma unroll
                    for (int tc = 0; tc < 4; ++tc)
                        lds[ro * 256 + ch * 128 + tc * 32 + l31] =
                            (EPI == 0) ? acc[tr][tc][i] : acc[tr][tc][i];
                }
            }
            __syncthreads();
            const unsigned* ldsu = (const unsigned*)lds;
            #pragma unroll
            for (int k = 0; k < 8; ++k) {
                const int flat = k * 1024 + tid * 4;   // u32 index in 32x256
                const int gr   = bm0 + p * 32 + (flat >> 8);
                if (gr < M) {
                    uint4 v = *(const uint4*)&ldsu[flat];
                    *(uint4*)&outu[(size_t)(bm0 + p * 32) * 256 + flat] = v;
                }
            }
        }
        return;
    }

    // EPI == 2: fused head matvec
    {
        float wv[4];
        #pragma unroll
        for (int tc = 0; tc < 4; ++tc) wv[tc] = wd2[ch * 128 + tc * 32 + l31];
        float dd[2][16];
        #pragma unroll
        for (int tr = 0; tr < 2; ++tr)
            #pragma unroll
            for (int i = 0; i < 16; ++i) {
                float s = 0.f;
                #pragma unroll
                for (int tc = 0; tc < 4; ++tc) s += acc[tr][tc][i] * wv[tc];
                #pragma unroll
                for (int m = 1; m < 32; m <<= 1) s += __shfl_xor(s, m);
                dd[tr][i] = s;
            }
        const int j  = l31;
        const int ji = j & 15, jt = j >> 4;
        red[ch * 128 + rh * 64 + jt * 32 + 4 * lh + (ji & 3) + 8 * (ji >> 2)] = dd[jt][ji];
        __syncthreads();
        if (tid < 128) {
            const int gr = bm0 + tid;
            if (gr < M) out1[gr] = red[tid] + red[128 + tid] + bd2[0];
        }
    }
}

// ---- layer-1 GEMM with fused bucket-scatter (tail blocks FIRST) ----
__global__ __launch_bounds__(256, 2)
void gemm_l1(const void* __restrict__ Av, const _Float16* __restrict__ wpk,
             const float* __restrict__ bA, const float* __restrict__ bB,
             void* __restrict__ outv, int M,
             const int* __restrict__ ei, int E, int nb,
             int* __restrict__ gcur, int2* __restrict__ ebuf)
{
    if ((int)blockIdx.x >= TB) {
        gemm2_body<0, 1>(Av, wpk, bA, bB, outv, nullptr, nullptr, nullptr, M,
                         ((int)blockIdx.x - TB) * BM);
    } else {
        __shared__ int h[NBMAX], cur[NBMAX];
        const int tid = threadIdx.x;
        const int b   = (int)blockIdx.x;            // 0..TB-1
        for (int t = tid; t < nb; t += 256) h[t] = 0;
        __syncthreads();
        const int EB = (E + TB - 1) / TB;
        const int e0 = b * EB, e1 = min(E, e0 + EB);
        for (int e = e0 + tid; e < e1; e += 256)
            atomicAdd(&h[ei[E + e] >> 8], 1);
        __syncthreads();
        for (int t = tid; t < nb; t += 256)
            cur[t] = atomicAdd(&gcur[t], h[t]);
        __syncthreads();
        for (int e = e0 + tid; e < e1; e += 256) {
            const int d = ei[E + e];
            const int p = atomicAdd(&cur[d >> 8], 1);
            ebuf[p] = make_int2(d, ei[e]);
        }
    }
}

__global__ __launch_bounds__(256, 2)
void gemm_z(const void* __restrict__ Av, const _Float16* __restrict__ wpk,
            void* __restrict__ outv, int M)
{
    gemm2_body<1, 0>(Av, wpk, nullptr, nullptr, outv, nullptr, nullptr, nullptr,
                     M, (int)blockIdx.x * BM);
}

__global__ __launch_bounds__(256, 2)
void gemm_head(const void* __restrict__ Av, const _Float16* __restrict__ wpk,
               const float* __restrict__ bA, const float* __restrict__ bB,
               const float* __restrict__ wd2, const float* __restrict__ bd2,
               float* __restrict__ out1, int M)
{
    gemm2_body<1, 2>(Av, wpk, bA, bB, nullptr, wd2, bd2, out1, M,
                     (int)blockIdx.x * BM);
}

// ------------------------- bucket CSR build -------------------------

__global__ __launch_bounds__(512)
void scanb_kernel(const int* __restrict__ ghist, int* __restrict__ gboff,
                  int* __restrict__ gcur, int* __restrict__ rp, int M, int E,
                  int nb)
{
    __shared__ int sm[512];
    const int tid = threadIdx.x;
    const int v = (tid < nb) ? ghist[tid] : 0;
    sm[tid] = v;
    __syncthreads();
    for (int off = 1; off < 512; off <<= 1) {
        int t = (tid >= off) ? sm[tid - off] : 0;
        __syncthreads();
        sm[tid] += t;
        __syncthreads();
    }
    if (tid < nb) {
        const int ex = sm[tid] - v;
        gboff[tid] = ex;
        gcur[tid]  = ex;
    }
    if (tid == 0) { gboff[nb] = E; rp[M] = E; }
}

__global__ __launch_bounds__(256)
void bucket_kernel(const int2* __restrict__ ebuf, const int* __restrict__ gboff,
                   int* __restrict__ rp, int* __restrict__ esrc, int M)
{
    const int b   = (int)blockIdx.x;
    const int tid = threadIdx.x;
    const int base = gboff[b], top = gboff[b + 1];
    const int d0 = b << 8;
    __shared__ int c[256], sm[256], cur[256];
    c[tid] = 0;
    __syncthreads();
    for (int j = base + tid; j < top; j += 256)
        atomicAdd(&c[ebuf[j].x - d0], 1);
    __syncthreads();
    sm[tid] = c[tid];
    __syncthreads();
    for (int off = 1; off < 256; off <<= 1) {
        int t = (tid >= off) ? sm[tid - off] : 0;
        __syncthreads();
        sm[tid] += t;
        __syncthreads();
    }
    const int excl = sm[tid] - c[tid];
    const int d = d0 + tid;
    if (d < M) rp[d] = base + excl;
    cur[tid] = base + excl;
    __syncthreads();
    for (int j = base + tid; j < top; j += 256) {
        const int2 e = ebuf[j];
        const int p = atomicAdd(&cur[e.x - d0], 1);
        esrc[p] = e.y;
    }
}

// ---- finalize: h[v] = l2norm(relu([z1[v]+b2 | segsum(z2[src])+b3])) ----
// One wave per node. z1/esrc streamed nontemporal, hp stored nontemporal
// (each touched once) so the LLC keeps the z2 gather set resident.
__global__ __launch_bounds__(256)
void fin_kernel(const float* __restrict__ z, const int* __restrict__ rp,
                const int* __restrict__ esrc,
                const float* __restrict__ b2, const float* __restrict__ b3,
                unsigned* __restrict__ hp, int M)
{
    const int v    = blockIdx.x * 4 + (threadIdx.x >> 6);
    const int lane = threadIdx.x & 63;
    if (v >= M) return;
    const int beg = rp[v], end = rp[v + 1];
    const int deg = end - beg;

    const float2 z1 = ntld_f2(&z[(size_t)v * DIM + lane * 2]);
    const float2 c2 = *(const float2*)&b2[lane * 2];
    const float2 c3 = *(const float2*)&b3[lane * 2];

    const float* z2 = z + 128;
    float ax0 = 0.f, ay0 = 0.f, ax1 = 0.f, ay1 = 0.f;
    float ax2 = 0.f, ay2 = 0.f, ax3 = 0.f, ay3 = 0.f;

    for (int base = 0; base < deg; base += 64) {
        const int cnt = min(64, deg - base);
        int myidx = 0;
        if (lane < cnt)
            myidx = __builtin_nontemporal_load(&esrc[beg + base + lane]);
        int j = 0;
        for (; j + 3 < cnt; j += 4) {
            const int s0 = __builtin_amdgcn_readlane(myidx, j);
            const int s1 = __builtin_amdgcn_readlane(myidx, j + 1);
            const int s2 = __builtin_amdgcn_readlane(myidx, j + 2);
            const int s3 = __builtin_amdgcn_readlane(myidx, j + 3);
            const float2 g0 = *(const float2*)&z2[(size_t)s0 * DIM + lane * 2];
            const float2 g1 = *(const float2*)&z2[(size_t)s1 * DIM + lane * 2];
            const float2 g2 = *(const float2*)&z2[(size_t)s2 * DIM + lane * 2];
            const float2 g3 = *(const float2*)&z2[(size_t)s3 * DIM + lane * 2];
            ax0 += g0.x; ay0 += g0.y;
            ax1 += g1.x; ay1 += g1.y;
            ax2 += g2.x; ay2 += g2.y;
            ax3 += g3.x; ay3 += g3.y;
        }
        for (; j < cnt; ++j) {
            const int s0 = __builtin_amdgcn_readlane(myidx, j);
            const float2 g0 = *(const float2*)&z2[(size_t)s0 * DIM + lane * 2];
            ax0 += g0.x; ay0 += g0.y;
        }
    }
    const float sx = (ax0 + ax1) + (ax2 + ax3);
    const float sy = (ay0 + ay1) + (ay2 + ay3);

    const float u1x = fmaxf(z1.x + c2.x, 0.f), u1y = fmaxf(z1.y + c2.y, 0.f);
    const float u2x = fmaxf(sx + c3.x, 0.f),  u2y = fmaxf(sy + c3.y, 0.f);

    float ss = u1x * u1x + u1y * u1y + u2x * u2x + u2y * u2y;
    #pragma unroll
    for (int off = 32; off > 0; off >>= 1) ss += __shfl_xor(ss, off);
    const float inv = 1.0f / sqrtf(ss);

    uint2 p1; p1.x = pack_pair(u1x * inv); p1.y = pack_pair(u1y * inv);
    uint2 p2; p2.x = pack_pair(u2x * inv); p2.y = pack_pair(u2y * inv);
    __builtin_nontemporal_store(
        __builtin_bit_cast(unsigned long long, p1),
        (unsigned long long*)&hp[(size_t)v * DIM + lane * 2]);
    __builtin_nontemporal_store(
        __builtin_bit_cast(unsigned long long, p2),
        (unsigned long long*)&hp[(size_t)v * DIM + 128 + lane * 2]);
}

// ------------------------- launch -------------------------

extern "C" void kernel_launch(void* const* d_in, const int* in_sizes, int n_in,
                              void* d_out, int out_size, void* d_ws, size_t ws_size,
                              hipStream_t stream)
{
    const float* x   = (const float*)d_in[0];
    const int*   ei  = (const int*)d_in[1];
    const float* W1  = (const float*)d_in[2];
    const float* b1  = (const float*)d_in[3];
    const float* W2  = (const float*)d_in[4];
    const float* b2  = (const float*)d_in[5];
    const float* W3  = (const float*)d_in[6];
    const float* b3  = (const float*)d_in[7];
    const float* Wd1 = (const float*)d_in[8];
    const float* bd1 = (const float*)d_in[9];
    const float* Wd2 = (const float*)d_in[10];
    const float* bd2 = (const float*)d_in[11];
    float* out = (float*)d_out;

    const int M = in_sizes[0] / DIM;   // 100000
    const int E = in_sizes[1] / 2;     // 1600000
    const int nb = (M + 255) >> 8;     // 391 buckets of 256 dsts

    unsigned* hp  = (unsigned*)d_ws;                  // M*256 u32 (hi,lo) pairs
    float*    z   = (float*)(hp + (size_t)M * DIM);   // M*256 f32
    int*   rp     = (int*)(z + (size_t)M * DIM);      // M+1
    int*   esrc   = rp + (M + 1);                     // E
    int*   ghist  = esrc + E;                         // nb
    int*   gboff  = ghist + nb;                       // nb+1
    int*   gcur   = gboff + nb + 1;                   // nb
    int2*  ebuf   = (int2*)z;                         // aliases z (disjoint in time)

    // packed weights (256 KB each), 256-B aligned
    size_t woff = (size_t)((char*)(gcur + nb) - (char*)d_ws);
    woff = (woff + 255) & ~(size_t)255;
    _Float16* wpk1 = (_Float16*)((char*)d_ws + woff);
    _Float16* wpk2 = wpk1 + 131072;
    _Float16* wpkd = wpk2 + 131072;

    hipMemsetAsync(ghist, 0, sizeof(int) * nb, stream);

    const int gb  = (M + BM - 1) / BM;       // 782 gemm blocks
    const int fb  = (M + 3) / 4;             // fin: 4 nodes (waves) per block

    // one-time W pack (blocks 0..191) + edge bucket histogram (192..319)
    pack_hist_kernel<<<320, 256, 0, stream>>>(
        W1, W1 + 128 * DIM, W2, W3, Wd1, Wd1 + 128 * DIM, wpk1, wpk2, wpkd,
        ei, E, nb, ghist);

    // bucket scan -> offsets
    scanb_kernel<<<1, 512, 0, stream>>>(ghist, gboff, gcur, rp, M, E, nb);

    // layer-1 GEMM + bucket-scatter (scatter blocks FIRST -> overlapped)
    gemm_l1<<<TB + gb, 256, 0, stream>>>(
        x, wpk1, b1, b1 + 128, hp, M, ei, E, nb, gcur, ebuf);

    // per-bucket CSR finalize: rp + esrc
    bucket_kernel<<<nb, 256, 0, stream>>>(ebuf, gboff, rp, esrc, M);

    // z GEMM #1, finalize
    gemm_z<<<gb, 256, 0, stream>>>(hp, wpk2, z, M);
    fin_kernel<<<fb, 256, 0, stream>>>(z, rp, esrc, b2, b3, hp, M);

    // z GEMM #2, finalize
    gemm_z<<<gb, 256, 0, stream>>>(hp, wpk2, z, M);
    fin_kernel<<<fb, 256, 0, stream>>>(z, rp, esrc, b2, b3, hp, M);

    // head: out = relu(h @ Wd1^T + bd1) @ Wd2^T + bd2
    gemm_head<<<gb, 256, 0, stream>>>(
        hp, wpkd, bd1, bd1 + 128, Wd2, bd2, out, M);
}

// Round 8
// 701.968 us; speedup vs baseline: 1.2026x; 1.0008x over previous
//
#include <hip/hip_runtime.h>
#include <math.h>

// ---------------------------------------------------------------------------
// DQNNet GNN, f16x3 split-precision MFMA GEMMs (error ~2^-22, fp32-equivalent).
//   h = l2norm(relu(x @ W1^T + b1))            [gemm_l1, + fused bucket-scatter]
//   2x: z = h @ [W2;W3]^T                      [gemm_z]
//       h = l2norm(relu([z1+b2 | segsum(z2[src])+b3]))   [fin]
//   out = relu(h @ Wd1^T + bd1) @ Wd2^T + bd2  [gemm_head, matvec fused]
//
// v9: revert to the v7 (passing) structure; fin gather pipeline deepened
// 4 -> 8 independent 512B gathers in flight per wave; all nontemporal hints
// removed (they evicted hp/esrc from LLC right before their consumers).
// GEMM: A staged via global_load_lds w=16 (K-sliced, double-buffered,
// source-addr swizzle), W packed fragment-major hi/lo + register-prefetched,
// C-write staged through LDS for 1KB-contiguous stores.
// h stored as (hi,lo) f16 pairs packed in u32 (same bytes as fp32).
// ---------------------------------------------------------------------------

typedef _Float16 f16x8 __attribute__((ext_vector_type(8)));
typedef float    f32x16 __attribute__((ext_vector_type(16)));

constexpr int DIM = 256;
constexpr int BM  = 128;
constexpr int NBMAX = 392; // max buckets (256 dsts each): M<=100352
constexpr int TB   = 192;  // scatter blocks in l1 (run first)

__device__ __forceinline__ unsigned pack_pair(float v) {
    _Float16 hi = (_Float16)v;
    _Float16 lo = (_Float16)(v - (float)hi);
    return (unsigned)__builtin_bit_cast(unsigned short, hi)
         | ((unsigned)__builtin_bit_cast(unsigned short, lo) << 16);
}

__device__ __forceinline__ void glds16(const void* g, void* l) {
    __builtin_amdgcn_global_load_lds(
        (const __attribute__((address_space(1))) unsigned*)g,
        (__attribute__((address_space(3))) unsigned*)l, 16, 0, 0);
}

// ---- fused one-time W pack (blocks 0..191) + edge histogram (192..319) ----
// pack dst layout: frag = (((hl*8 + t)*2 + ks)*8 + nt), slot = frag*64 + lane,
// 8 f16 per slot: W[n = nt*32 + (lane&31)][k = t*32 + ks*16 + (lane>>5)*8 + j]
__global__ __launch_bounds__(256)
void pack_hist_kernel(const float* __restrict__ WA0, const float* __restrict__ WB0,
                      const float* __restrict__ WA1, const float* __restrict__ WB1,
                      const float* __restrict__ WA2, const float* __restrict__ WB2,
                      _Float16* __restrict__ d0, _Float16* __restrict__ d1,
                      _Float16* __restrict__ d2,
                      const int* __restrict__ ei, int E, int nb,
                      int* __restrict__ ghist)
{
    if ((int)blockIdx.x < 192) {
        const int layer = (int)blockIdx.x >> 6;
        const int tid   = ((int)blockIdx.x & 63) * 256 + threadIdx.x;  // 0..16383
        const float* WA = layer == 0 ? WA0 : layer == 1 ? WA1 : WA2;
        const float* WB = layer == 0 ? WB0 : layer == 1 ? WB1 : WB2;
        _Float16* dst   = layer == 0 ? d0  : layer == 1 ? d1  : d2;

        const int lane = tid & 63;
        const int frag = tid >> 6;               // 0..255
        const int nt = frag & 7;
        const int ks = (frag >> 3) & 1;
        const int t  = (frag >> 4) & 7;
        const int hl = frag >> 7;
        const int n  = nt * 32 + (lane & 31);
        const int k0 = t * 32 + ks * 16 + (lane >> 5) * 8;
        const float* src = (n < 128) ? &WA[(size_t)n * 256]
                                     : &WB[(size_t)(n - 128) * 256];
        f16x8 o;
        #pragma unroll
        for (int j = 0; j < 8; ++j) {
            const float v = src[k0 + j];
            const _Float16 h = (_Float16)v;
            o[j] = hl ? (_Float16)(v - (float)h) : h;
        }
        *(f16x8*)&dst[(size_t)tid * 8] = o;
    } else {
        __shared__ int h[NBMAX];
        const int tid = threadIdx.x;
        const int b   = (int)blockIdx.x - 192;   // 0..127
        for (int t = tid; t < nb; t += 256) h[t] = 0;
        __syncthreads();
        const int EB = (E + 127) >> 7;
        const int e0 = b * EB, e1 = min(E, e0 + EB);
        for (int e = e0 + tid; e < e1; e += 256)
            atomicAdd(&h[ei[E + e] >> 8], 1);
        __syncthreads();
        for (int t = tid; t < nb; t += 256)
            if (h[t]) atomicAdd(&ghist[t], h[t]);
    }
}

// ---------------------------------------------------------------------------
// GEMM body. BM=128 rows/block, 4 waves: rh = w>>1 (64-row half),
// ch = w&1 (128-col half). Per wave: acc[2][4] f32x16 = 64x128 output.
// AMODE: 0 = A is fp32 (cvt-split at read); 1 = A is (hi,lo)-pair u32 (perm).
// EPI:   0 = raw fp32 z; 1 = bias+relu+l2norm -> pair; 2 = bias+relu+matvec.
// ---------------------------------------------------------------------------
template <int AMODE, int EPI>
__device__ __forceinline__
void gemm2_body(const void* __restrict__ Av, const _Float16* __restrict__ Wpk,
                const float* __restrict__ bA, const float* __restrict__ bB,
                void* __restrict__ outv,
                const float* __restrict__ wd2, const float* __restrict__ bd2,
                float* __restrict__ out1, int M, int bm0)
{
    // A tile double buffer: [buf][row 0..127][32 u32 = 8 chunks of 16B]
    // Also reused as the 32KB epilogue staging buffer / red[].
    __shared__ __align__(16) unsigned smem[2][128][32];   // 32 KB

    const int tid  = threadIdx.x;
    const int lane = tid & 63;
    const int w    = tid >> 6;
    const int rh   = w >> 1;
    const int ch   = w & 1;
    const int l31  = lane & 31;
    const int lh   = lane >> 5;

    // W: fragment-major; hi at base, lo at +131072 B;
    // frag byte = s*8192 + tc*1024 + (ch*4*64 + lane)*16.
    const char* wh_p = (const char*)Wpk + (size_t)(ch * 4 * 64 + lane) * 16;
    const char* wl_p = wh_p + 131072;

    // staging geometry: wave w stages rows [w*32, w*32+32), 4 instrs of
    // 1KB (8 rows x 8 chunks); lane -> (row = +lane>>3, chunk = lane&7).
    const int srb  = w * 32;
    const int srow = lane >> 3;
    const int scp  = lane & 7;

    f32x16 acc[2][4];
    #pragma unroll
    for (int tr = 0; tr < 2; ++tr)
        #pragma unroll
        for (int tc = 0; tc < 4; ++tc)
            #pragma unroll
            for (int i = 0; i < 16; ++i) acc[tr][tc][i] = 0.0f;

    f16x8 WH0[4], WL0[4], WH1[4], WL1[4];

    auto STAGE = [&](int t, int b) {
        #pragma unroll
        for (int i = 0; i < 4; ++i) {
            const int r  = srb + i * 8 + srow;
            const int rg = min(bm0 + r, M - 1);          // clamp; stores guarded
            const int cl = scp ^ (r & 7);                // source pre-swizzle
            glds16((const char*)Av + (size_t)rg * 1024 + t * 128 + cl * 16,
                   (void*)&smem[b][srb + i * 8][0]);     // uniform base +lane*16
        }
    };
    auto PW = [&](int s, f16x8* WH, f16x8* WL) {
        #pragma unroll
        for (int tc = 0; tc < 4; ++tc) {
            WH[tc] = *(const f16x8*)(wh_p + (size_t)s * 8192 + tc * 1024);
            WL[tc] = *(const f16x8*)(wl_p + (size_t)s * 8192 + tc * 1024);
        }
    };
    auto LOADA = [&](int b, int ks, f16x8* ah, f16x8* al) {
        #pragma unroll
        for (int tr = 0; tr < 2; ++tr) {
            const int r  = rh * 64 + tr * 32 + l31;
            const int sw = r & 7;
            const int c0 = ks * 4 + lh * 2;
            const unsigned* Ar = &smem[b][r][0];
            const uint4 q0 = *(const uint4*)&Ar[((c0    ) ^ sw) * 4];
            const uint4 q1 = *(const uint4*)&Ar[((c0 + 1) ^ sw) * 4];
            if (AMODE == 1) {
                uint4 uh, ul;
                uh.x = __builtin_amdgcn_perm(q0.y, q0.x, 0x05040100u);
                uh.y = __builtin_amdgcn_perm(q0.w, q0.z, 0x05040100u);
                uh.z = __builtin_amdgcn_perm(q1.y, q1.x, 0x05040100u);
                uh.w = __builtin_amdgcn_perm(q1.w, q1.z, 0x05040100u);
                ul.x = __builtin_amdgcn_perm(q0.y, q0.x, 0x07060302u);
                ul.y = __builtin_amdgcn_perm(q0.w, q0.z, 0x07060302u);
                ul.z = __builtin_amdgcn_perm(q1.y, q1.x, 0x07060302u);
                ul.w = __builtin_amdgcn_perm(q1.w, q1.z, 0x07060302u);
                ah[tr] = __builtin_bit_cast(f16x8, uh);
                al[tr] = __builtin_bit_cast(f16x8, ul);
            } else {
                const float fv[8] = {
                    __builtin_bit_cast(float, q0.x), __builtin_bit_cast(float, q0.y),
                    __builtin_bit_cast(float, q0.z), __builtin_bit_cast(float, q0.w),
                    __builtin_bit_cast(float, q1.x), __builtin_bit_cast(float, q1.y),
                    __builtin_bit_cast(float, q1.z), __builtin_bit_cast(float, q1.w)};
                #pragma unroll
                for (int j = 0; j < 8; ++j) {
                    const _Float16 h = (_Float16)fv[j];
                    ah[tr][j] = h;
                    al[tr][j] = (_Float16)(fv[j] - (float)h);
                }
            }
        }
    };
    auto MF = [&](const f16x8* ah, const f16x8* al,
                  const f16x8* WH, const f16x8* WL) {
        // per-acc order matches v0 exactly: ah*wh, ah*wl, al*wh
        #pragma unroll
        for (int tr = 0; tr < 2; ++tr)
            #pragma unroll
            for (int tc = 0; tc < 4; ++tc) {
                acc[tr][tc] = __builtin_amdgcn_mfma_f32_32x32x16_f16(ah[tr], WH[tc], acc[tr][tc], 0, 0, 0);
                acc[tr][tc] = __builtin_amdgcn_mfma_f32_32x32x16_f16(ah[tr], WL[tc], acc[tr][tc], 0, 0, 0);
                acc[tr][tc] = __builtin_amdgcn_mfma_f32_32x32x16_f16(al[tr], WH[tc], acc[tr][tc], 0, 0, 0);
            }
    };

    STAGE(0, 0);
    PW(0, WH0, WL0);

    #pragma unroll 1
    for (int t = 0; t < 8; ++t) {
        __syncthreads();                       // drains vmcnt -> buf[t&1] ready
        if (t < 7) STAGE(t + 1, (t + 1) & 1);  // in flight until next barrier
        const int b = t & 1;
        {   // ks = 0 (k-step s = 2t), uses set0; prefetch s+1 -> set1
            if (2 * t + 1 < 16) PW(2 * t + 1, WH1, WL1);
            f16x8 ah[2], al[2];
            LOADA(b, 0, ah, al);
            MF(ah, al, WH0, WL0);
        }
        {   // ks = 1 (s = 2t+1), uses set1; prefetch s+1 -> set0
            if (2 * t + 2 < 16) PW(2 * t + 2, WH0, WL0);
            f16x8 ah[2], al[2];
            LOADA(b, 1, ah, al);
            MF(ah, al, WH1, WL1);
        }
    }
    __syncthreads();   // LDS reads done before epilogue reuses smem

    // C/D layout (32x32): col = lane&31, row = (reg&3) + 8*(reg>>2) + 4*(lane>>5)

    float* red = (float*)smem;

    if (EPI != 0) {   // bias + relu
        float bias[4];
        #pragma unroll
        for (int tc = 0; tc < 4; ++tc)
            bias[tc] = (ch ? bB : bA)[tc * 32 + l31];
        #pragma unroll
        for (int tr = 0; tr < 2; ++tr)
            #pragma unroll
            for (int tc = 0; tc < 4; ++tc)
                #pragma unroll
                for (int i = 0; i < 16; ++i)
                    acc[tr][tc][i] = fmaxf(acc[tr][tc][i] + bias[tc], 0.0f);
    }

    if (EPI == 1) {   // l2norm factors, then pack into acc in place
        float ss[2][16];
        #pragma unroll
        for (int tr = 0; tr < 2; ++tr)
            #pragma unroll
            for (int i = 0; i < 16; ++i) {
                float s = 0.f;
                #pragma unroll
                for (int tc = 0; tc < 4; ++tc) s += acc[tr][tc][i] * acc[tr][tc][i];
                #pragma unroll
                for (int m = 1; m < 32; m <<= 1) s += __shfl_xor(s, m);
                ss[tr][i] = s;
            }
        const int j  = l31;
        const int ji = j & 15, jt = j >> 4;
        red[ch * 128 + rh * 64 + jt * 32 + 4 * lh + (ji & 3) + 8 * (ji >> 2)] = ss[jt][ji];
        __syncthreads();
        #pragma unroll
        for (int tr = 0; tr < 2; ++tr)
            #pragma unroll
            for (int i = 0; i < 16; ++i) {
                const int rl = rh * 64 + tr * 32 + 4 * lh + (i & 3) + 8 * (i >> 2);
                const float inv = 1.0f / sqrtf(red[rl] + red[128 + rl]);
                #pragma unroll
                for (int tc = 0; tc < 4; ++tc)
                    acc[tr][tc][i] = __builtin_bit_cast(float,
                        pack_pair(acc[tr][tc][i] * inv));
            }
        // pass loop's first barrier separates red[] reads from LDS overwrite
    }

    if (EPI == 0 || EPI == 1) {
        // staged coalesced C-write: 4 passes of 32 rows through 32KB LDS;
        // final stores are 16B/lane, wave-contiguous (1KB per instruction).
        float* lds = (float*)smem;
        unsigned* outu = (unsigned*)outv;
        #pragma unroll
        for (int p = 0; p < 4; ++p) {
            __syncthreads();               // prev pass consumed / red[] done
            if (rh == (p >> 1)) {
                const int tr = p & 1;
                #pragma unroll
                for (int i = 0; i < 16; ++i) {
                    const int ro = 4 * lh + (i & 3) + 8 * (i >> 2);   // 0..31
                    #pragma unroll
                    for (int tc = 0; tc < 4; ++tc)
                        lds[ro * 256 + ch * 128 + tc * 32 + l31] =
                            (EPI == 0) ? acc[tr][tc][i] : acc[tr][tc][i];
                }
            }
            __syncthreads();
            const unsigned* ldsu = (const unsigned*)lds;
            #pragma unroll
            for (int k = 0; k < 8; ++k) {
                const int flat = k * 1024 + tid * 4;   // u32 index in 32x256
                const int gr   = bm0 + p * 32 + (flat >> 8);
                if (gr < M) {
                    uint4 v = *(const uint4*)&ldsu[flat];
                    *(uint4*)&outu[(size_t)(bm0 + p * 32) * 256 + flat] = v;
                }
            }
        }
        return;
    }

    // EPI == 2: fused head matvec
    {
        float wv[4];
        #pragma unroll
        for (int tc = 0; tc < 4; ++tc) wv[tc] = wd2[ch * 128 + tc * 32 + l31];
        float dd[2][16];
        #pragma unroll
        for (int tr = 0; tr < 2; ++tr)
            #pragma unroll
            for (int i = 0; i < 16; ++i) {
                float s = 0.f;
                #pragma unroll
                for (int tc = 0; tc < 4; ++tc) s += acc[tr][tc][i] * wv[tc];
                #pragma unroll
                for (int m = 1; m < 32; m <<= 1) s += __shfl_xor(s, m);
                dd[tr][i] = s;
            }
        const int j  = l31;
        const int ji = j & 15, jt = j >> 4;
        red[ch * 128 + rh * 64 + jt * 32 + 4 * lh + (ji & 3) + 8 * (ji >> 2)] = dd[jt][ji];
        __syncthreads();
        if (tid < 128) {
            const int gr = bm0 + tid;
            if (gr < M) out1[gr] = red[tid] + red[128 + tid] + bd2[0];
        }
    }
}

// ---- layer-1 GEMM with fused bucket-scatter (scatter blocks FIRST) ----
__global__ __launch_bounds__(256, 2)
void gemm_l1(const void* __restrict__ Av, const _Float16* __restrict__ wpk,
             const float* __restrict__ bA, const float* __restrict__ bB,
             void* __restrict__ outv, int M,
             const int* __restrict__ ei, int E, int nb,
             int* __restrict__ gcur, int2* __restrict__ ebuf)
{
    if ((int)blockIdx.x >= TB) {
        gemm2_body<0, 1>(Av, wpk, bA, bB, outv, nullptr, nullptr, nullptr, M,
                         ((int)blockIdx.x - TB) * BM);
    } else {
        __shared__ int h[NBMAX], cur[NBMAX];
        const int tid = threadIdx.x;
        const int b   = (int)blockIdx.x;            // 0..TB-1
        for (int t = tid; t < nb; t += 256) h[t] = 0;
        __syncthreads();
        const int EB = (E + TB - 1) / TB;
        const int e0 = b * EB, e1 = min(E, e0 + EB);
        for (int e = e0 + tid; e < e1; e += 256)
            atomicAdd(&h[ei[E + e] >> 8], 1);
        __syncthreads();
        for (int t = tid; t < nb; t += 256)
            cur[t] = atomicAdd(&gcur[t], h[t]);
        __syncthreads();
        for (int e = e0 + tid; e < e1; e += 256) {
            const int d = ei[E + e];
            const int p = atomicAdd(&cur[d >> 8], 1);
            ebuf[p] = make_int2(d, ei[e]);
        }
    }
}

__global__ __launch_bounds__(256, 2)
void gemm_z(const void* __restrict__ Av, const _Float16* __restrict__ wpk,
            void* __restrict__ outv, int M)
{
    gemm2_body<1, 0>(Av, wpk, nullptr, nullptr, outv, nullptr, nullptr, nullptr,
                     M, (int)blockIdx.x * BM);
}

__global__ __launch_bounds__(256, 2)
void gemm_head(const void* __restrict__ Av, const _Float16* __restrict__ wpk,
               const float* __restrict__ bA, const float* __restrict__ bB,
               const float* __restrict__ wd2, const float* __restrict__ bd2,
               float* __restrict__ out1, int M)
{
    gemm2_body<1, 2>(Av, wpk, bA, bB, nullptr, wd2, bd2, out1, M,
                     (int)blockIdx.x * BM);
}

// ------------------------- bucket CSR build -------------------------

__global__ __launch_bounds__(512)
void scanb_kernel(const int* __restrict__ ghist, int* __restrict__ gboff,
                  int* __restrict__ gcur, int* __restrict__ rp, int M, int E,
                  int nb)
{
    __shared__ int sm[512];
    const int tid = threadIdx.x;
    const int v = (tid < nb) ? ghist[tid] : 0;
    sm[tid] = v;
    __syncthreads();
    for (int off = 1; off < 512; off <<= 1) {
        int t = (tid >= off) ? sm[tid - off] : 0;
        __syncthreads();
        sm[tid] += t;
        __syncthreads();
    }
    if (tid < nb) {
        const int ex = sm[tid] - v;
        gboff[tid] = ex;
        gcur[tid]  = ex;
    }
    if (tid == 0) { gboff[nb] = E; rp[M] = E; }
}

__global__ __launch_bounds__(256)
void bucket_kernel(const int2* __restrict__ ebuf, const int* __restrict__ gboff,
                   int* __restrict__ rp, int* __restrict__ esrc, int M)
{
    const int b   = (int)blockIdx.x;
    const int tid = threadIdx.x;
    const int base = gboff[b], top = gboff[b + 1];
    const int d0 = b << 8;
    __shared__ int c[256], sm[256], cur[256];
    c[tid] = 0;
    __syncthreads();
    for (int j = base + tid; j < top; j += 256)
        atomicAdd(&c[ebuf[j].x - d0], 1);
    __syncthreads();
    sm[tid] = c[tid];
    __syncthreads();
    for (int off = 1; off < 256; off <<= 1) {
        int t = (tid >= off) ? sm[tid - off] : 0;
        __syncthreads();
        sm[tid] += t;
        __syncthreads();
    }
    const int excl = sm[tid] - c[tid];
    const int d = d0 + tid;
    if (d < M) rp[d] = base + excl;
    cur[tid] = base + excl;
    __syncthreads();
    for (int j = base + tid; j < top; j += 256) {
        const int2 e = ebuf[j];
        const int p = atomicAdd(&cur[e.x - d0], 1);
        esrc[p] = e.y;
    }
}

// ---- finalize: h[v] = l2norm(relu([z1[v]+b2 | segsum(z2[src])+b3])) ----
// One wave per node. Edge indices preloaded 64-wide (one coalesced load),
// broadcast via v_readlane; 8 independent accumulators keep 8 gathers of
// 512 B in flight per wave.
__global__ __launch_bounds__(256)
void fin_kernel(const float* __restrict__ z, const int* __restrict__ rp,
                const int* __restrict__ esrc,
                const float* __restrict__ b2, const float* __restrict__ b3,
                unsigned* __restrict__ hp, int M)
{
    const int v    = blockIdx.x * 4 + (threadIdx.x >> 6);
    const int lane = threadIdx.x & 63;
    if (v >= M) return;
    const int beg = rp[v], end = rp[v + 1];
    const int deg = end - beg;

    const float* z2 = z + 128;
    float ax[8], ay[8];
    #pragma unroll
    for (int q = 0; q < 8; ++q) { ax[q] = 0.f; ay[q] = 0.f; }

    for (int base = 0; base < deg; base += 64) {
        const int cnt = min(64, deg - base);
        int myidx = 0;
        if (lane < cnt) myidx = esrc[beg + base + lane];
        int j = 0;
        for (; j + 7 < cnt; j += 8) {
            int s[8];
            #pragma unroll
            for (int q = 0; q < 8; ++q)
                s[q] = __builtin_amdgcn_readlane(myidx, j + q);
            float2 g[8];
            #pragma unroll
            for (int q = 0; q < 8; ++q)
                g[q] = *(const float2*)&z2[(size_t)s[q] * DIM + lane * 2];
            #pragma unroll
            for (int q = 0; q < 8; ++q) { ax[q] += g[q].x; ay[q] += g[q].y; }
        }
        for (; j < cnt; ++j) {
            const int s0 = __builtin_amdgcn_readlane(myidx, j);
            const float2 g0 = *(const float2*)&z2[(size_t)s0 * DIM + lane * 2];
            ax[0] += g0.x; ay[0] += g0.y;
        }
    }
    const float sx = ((ax[0] + ax[1]) + (ax[2] + ax[3]))
                   + ((ax[4] + ax[5]) + (ax[6] + ax[7]));
    const float sy = ((ay[0] + ay[1]) + (ay[2] + ay[3]))
                   + ((ay[4] + ay[5]) + (ay[6] + ay[7]));

    const float2 z1 = *(const float2*)&z[(size_t)v * DIM + lane * 2];
    const float2 c2 = *(const float2*)&b2[lane * 2];
    const float2 c3 = *(const float2*)&b3[lane * 2];

    const float u1x = fmaxf(z1.x + c2.x, 0.f), u1y = fmaxf(z1.y + c2.y, 0.f);
    const float u2x = fmaxf(sx + c3.x, 0.f),  u2y = fmaxf(sy + c3.y, 0.f);

    float ss = u1x * u1x + u1y * u1y + u2x * u2x + u2y * u2y;
    #pragma unroll
    for (int off = 32; off > 0; off >>= 1) ss += __shfl_xor(ss, off);
    const float inv = 1.0f / sqrtf(ss);

    uint2 p1; p1.x = pack_pair(u1x * inv); p1.y = pack_pair(u1y * inv);
    uint2 p2; p2.x = pack_pair(u2x * inv); p2.y = pack_pair(u2y * inv);
    *(uint2*)&hp[(size_t)v * DIM + lane * 2]       = p1;
    *(uint2*)&hp[(size_t)v * DIM + 128 + lane * 2] = p2;
}

// ------------------------- launch -------------------------

extern "C" void kernel_launch(void* const* d_in, const int* in_sizes, int n_in,
                              void* d_out, int out_size, void* d_ws, size_t ws_size,
                              hipStream_t stream)
{
    const float* x   = (const float*)d_in[0];
    const int*   ei  = (const int*)d_in[1];
    const float* W1  = (const float*)d_in[2];
    const float* b1  = (const float*)d_in[3];
    const float* W2  = (const float*)d_in[4];
    const float* b2  = (const float*)d_in[5];
    const float* W3  = (const float*)d_in[6];
    const float* b3  = (const float*)d_in[7];
    const float* Wd1 = (const float*)d_in[8];
    const float* bd1 = (const float*)d_in[9];
    const float* Wd2 = (const float*)d_in[10];
    const float* bd2 = (const float*)d_in[11];
    float* out = (float*)d_out;

    const int M = in_sizes[0] / DIM;   // 100000
    const int E = in_sizes[1] / 2;     // 1600000
    const int nb = (M + 255) >> 8;     // 391 buckets of 256 dsts

    unsigned* hp  = (unsigned*)d_ws;                  // M*256 u32 (hi,lo) pairs
    float*    z   = (float*)(hp + (size_t)M * DIM);   // M*256 f32
    int*   rp     = (int*)(z + (size_t)M * DIM);      // M+1
    int*   esrc   = rp + (M + 1);                     // E
    int*   ghist  = esrc + E;                         // nb
    int*   gboff  = ghist + nb;                       // nb+1
    int*   gcur   = gboff + nb + 1;                   // nb
    int2*  ebuf   = (int2*)z;                         // aliases z (disjoint in time)

    // packed weights (256 KB each), 256-B aligned
    size_t woff = (size_t)((char*)(gcur + nb) - (char*)d_ws);
    woff = (woff + 255) & ~(size_t)255;
    _Float16* wpk1 = (_Float16*)((char*)d_ws + woff);
    _Float16* wpk2 = wpk1 + 131072;
    _Float16* wpkd = wpk2 + 131072;

    hipMemsetAsync(ghist, 0, sizeof(int) * nb, stream);

    const int gb  = (M + BM - 1) / BM;       // 782 gemm blocks
    const int fb  = (M + 3) / 4;             // fin: 4 nodes (waves) per block

    // one-time W pack (blocks 0..191) + edge bucket histogram (192..319)
    pack_hist_kernel<<<320, 256, 0, stream>>>(
        W1, W1 + 128 * DIM, W2, W3, Wd1, Wd1 + 128 * DIM, wpk1, wpk2, wpkd,
        ei, E, nb, ghist);

    // bucket scan -> offsets
    scanb_kernel<<<1, 512, 0, stream>>>(ghist, gboff, gcur, rp, M, E, nb);

    // layer-1 GEMM + bucket-scatter (scatter blocks FIRST -> overlapped)
    gemm_l1<<<TB + gb, 256, 0, stream>>>(
        x, wpk1, b1, b1 + 128, hp, M, ei, E, nb, gcur, ebuf);

    // per-bucket CSR finalize: rp + esrc
    bucket_kernel<<<nb, 256, 0, stream>>>(ebuf, gboff, rp, esrc, M);

    // z GEMM #1, finalize
    gemm_z<<<gb, 256, 0, stream>>>(hp, wpk2, z, M);
    fin_kernel<<<fb, 256, 0, stream>>>(z, rp, esrc, b2, b3, hp, M);

    // z GEMM #2, finalize
    gemm_z<<<gb, 256, 0, stream>>>(hp, wpk2, z, M);
    fin_kernel<<<fb, 256, 0, stream>>>(z, rp, esrc, b2, b3, hp, M);

    // head: out = relu(h @ Wd1^T + bd1) @ Wd2^T + bd2
    gemm_head<<<gb, 256, 0, stream>>>(
        hp, wpkd, bd1, bd1 + 128, Wd2, bd2, out, M);
}